// Round 1
// baseline (3213.054 us; speedup 1.0000x reference)
//
#include <hip/hip_runtime.h>
#include <math.h>

#define NN 50000
#define NE 800000
#define ET (NE + NN)      // 850000 edges incl self loops
#define FIN 128
#define DD 250
#define HD 256
#define NQ 200000
#define NEG_SLOPE 0.2f

// ---------------- CSR build ----------------

__global__ void count_kernel(const int* __restrict__ ei, int* __restrict__ cnt) {
    int k = blockIdx.x * 256 + threadIdx.x;
    if (k >= ET) return;
    int d = (k < NE) ? ei[NE + k] : (k - NE);
    atomicAdd(&cnt[d], 1);
}

__global__ void scan_kernel(const int* __restrict__ cnt, int* __restrict__ rowptr) {
    __shared__ int buf[1024];
    __shared__ int carry;
    int t = threadIdx.x;
    if (t == 0) carry = 0;
    __syncthreads();
    for (int base = 0; base < NN; base += 1024) {
        int i = base + t;
        int v = (i < NN) ? cnt[i] : 0;
        buf[t] = v;
        __syncthreads();
        for (int off = 1; off < 1024; off <<= 1) {
            int add = (t >= off) ? buf[t - off] : 0;
            __syncthreads();
            buf[t] += add;
            __syncthreads();
        }
        if (i < NN) rowptr[i] = carry + buf[t] - v;   // exclusive
        __syncthreads();
        if (t == 1023) carry += buf[1023];
        __syncthreads();
    }
    if (t == 0) rowptr[NN] = carry;
}

__global__ void scatter_kernel(const int* __restrict__ ei,
                               const int* __restrict__ rowptr,
                               int* __restrict__ fill,
                               int* __restrict__ ssrc, int* __restrict__ sdst) {
    int k = blockIdx.x * 256 + threadIdx.x;
    if (k >= ET) return;
    int s, d;
    if (k < NE) { s = ei[k]; d = ei[NE + k]; }
    else        { s = k - NE; d = k - NE; }
    int pos = rowptr[d] + atomicAdd(&fill[d], 1);
    ssrc[pos] = s;
    sdst[pos] = d;
}

// ---------------- generic fp32 GEMM: C[M,Dout] = A[M,K]@W[K,Dout] + b ----------------
// block 256 threads = one column each; 32 rows per block; A tile in LDS (broadcast reads)

__global__ __launch_bounds__(256) void gemm_kernel(
    const float* __restrict__ A, const float* __restrict__ W,
    const float* __restrict__ bias, float* __restrict__ C,
    int M, int K, int Dout, int dorelu)
{
    int KP = (K + 3) & ~3;
    extern __shared__ float a_lds[];   // 32 * KP
    int row0 = blockIdx.x * 32;
    int tid = threadIdx.x;
    int total = 32 * KP;
    for (int idx = tid; idx < total; idx += 256) {
        int r = idx / KP, k = idx - r * KP;
        float v = 0.f;
        int gr = row0 + r;
        if (gr < M && k < K) v = A[(size_t)gr * K + k];
        a_lds[idx] = v;
    }
    __syncthreads();
    int j = tid;
    bool active = (j < Dout);
    float acc[32];
#pragma unroll
    for (int q = 0; q < 32; q++) acc[q] = 0.f;
    for (int k = 0; k < KP; k += 4) {
        float w0 = 0.f, w1 = 0.f, w2 = 0.f, w3 = 0.f;
        if (active) {
            w0 = (k + 0 < K) ? W[(size_t)(k + 0) * Dout + j] : 0.f;
            w1 = (k + 1 < K) ? W[(size_t)(k + 1) * Dout + j] : 0.f;
            w2 = (k + 2 < K) ? W[(size_t)(k + 2) * Dout + j] : 0.f;
            w3 = (k + 3 < K) ? W[(size_t)(k + 3) * Dout + j] : 0.f;
        }
#pragma unroll
        for (int q = 0; q < 32; q++) {
            float4 p = *(const float4*)&a_lds[q * KP + k];
            acc[q] += p.x * w0 + p.y * w1 + p.z * w2 + p.w * w3;
        }
    }
    if (active) {
        float b = bias[j];
        int rmax = min(32, M - row0);
        for (int q = 0; q < rmax; q++) {
            float v = acc[q] + b;
            if (dorelu) v = fmaxf(v, 0.f);
            C[(size_t)(row0 + q) * Dout + j] = v;
        }
    }
}

// ---------------- edge score: e_k = att . leaky_relu(xl[src]+xr[dst]) ----------------
// one wave per edge

__global__ __launch_bounds__(256) void edge_score_kernel(
    const int* __restrict__ ssrc, const int* __restrict__ sdst,
    const float* __restrict__ xl, const float* __restrict__ xr,
    const float* __restrict__ att, float* __restrict__ e)
{
    int k = blockIdx.x * 4 + (threadIdx.x >> 6);
    if (k >= ET) return;
    int lane = threadIdx.x & 63;
    int s = ssrc[k], dd = sdst[k];
    const float* pl = xl + (size_t)s * DD;
    const float* pr = xr + (size_t)dd * DD;
    float p = 0.f;
    for (int d = lane; d < DD; d += 64) {
        float v = pl[d] + pr[d];
        v = (v > 0.f) ? v : NEG_SLOPE * v;
        p += att[d] * v;
    }
#pragma unroll
    for (int off = 32; off > 0; off >>= 1)
        p += __shfl_down(p, off, 64);
    if (lane == 0) e[k] = p;
}

// ---------------- per-dst softmax: overwrite e with alpha ----------------
// one wave per node (every node has >=1 edge due to self loop)

__global__ __launch_bounds__(256) void softmax_kernel(
    const int* __restrict__ rowptr, float* __restrict__ e)
{
    int i = blockIdx.x * 4 + (threadIdx.x >> 6);
    if (i >= NN) return;
    int lane = threadIdx.x & 63;
    int beg = rowptr[i], end = rowptr[i + 1];
    float m = -1e30f;
    for (int p = beg + lane; p < end; p += 64) m = fmaxf(m, e[p]);
#pragma unroll
    for (int off = 32; off > 0; off >>= 1)
        m = fmaxf(m, __shfl_xor(m, off, 64));
    float ssum = 0.f;
    for (int p = beg + lane; p < end; p += 64) ssum += expf(e[p] - m);
#pragma unroll
    for (int off = 32; off > 0; off >>= 1)
        ssum += __shfl_xor(ssum, off, 64);
    float inv = 1.f / ssum;
    for (int p = beg + lane; p < end; p += 64) e[p] = expf(e[p] - m) * inv;
}

// ---------------- aggregation: out[i,:] = sum alpha_k * xl[src_k,:] ----------------
// one block (256 thr) per dst node; thread = column

__global__ __launch_bounds__(256) void aggregate_kernel(
    const int* __restrict__ rowptr, const int* __restrict__ ssrc,
    const float* __restrict__ alpha, const float* __restrict__ xl,
    float* __restrict__ out, int dorelu)
{
    int i = blockIdx.x;
    int t = threadIdx.x;
    int beg = rowptr[i], end = rowptr[i + 1];
    float acc = 0.f;
    for (int p = beg; p < end; p++) {
        int s = ssrc[p];
        float a = alpha[p];
        if (t < DD) acc += a * xl[(size_t)s * DD + t];
    }
    if (t < DD) {
        if (dorelu) acc = fmaxf(acc, 0.f);
        out[(size_t)i * DD + t] = acc;
    }
}

// ---------------- head: out = relu(relu(concat(emb[a],emb[b])@Wm1+bm1)@Wm2+bm2) ----------------
// block 256 thr, 32 queries/block; thread = hidden unit j; pair tile in LDS

__global__ __launch_bounds__(256) void head_kernel(
    const int* __restrict__ query, const float* __restrict__ emb,
    const float* __restrict__ Wm1, const float* __restrict__ bm1,
    const float* __restrict__ Wm2, const float* __restrict__ bm2,
    float* __restrict__ out)
{
    __shared__ float pair[32][500];
    __shared__ float partial[32][4];
    int q0 = blockIdx.x * 32;
    int tid = threadIdx.x;
    for (int idx = tid; idx < 32 * 500; idx += 256) {
        int q = idx / 500, k = idx - q * 500;
        int node = (k < DD) ? query[(q0 + q) * 2 + 0] : query[(q0 + q) * 2 + 1];
        int kk = (k < DD) ? k : k - DD;
        pair[q][k] = emb[(size_t)node * DD + kk];
    }
    __syncthreads();
    int j = tid;
    float acc[32];
#pragma unroll
    for (int q = 0; q < 32; q++) acc[q] = 0.f;
    for (int k = 0; k < 500; k += 4) {
        float w0 = Wm1[(size_t)(k + 0) * HD + j];
        float w1 = Wm1[(size_t)(k + 1) * HD + j];
        float w2 = Wm1[(size_t)(k + 2) * HD + j];
        float w3 = Wm1[(size_t)(k + 3) * HD + j];
#pragma unroll
        for (int q = 0; q < 32; q++) {
            float4 p = *(const float4*)&pair[q][k];
            acc[q] += p.x * w0 + p.y * w1 + p.z * w2 + p.w * w3;
        }
    }
    float bj = bm1[j];
    float w2j = Wm2[j];
    int lane = tid & 63, wid = tid >> 6;
#pragma unroll
    for (int q = 0; q < 32; q++) {
        float v = fmaxf(acc[q] + bj, 0.f) * w2j;
#pragma unroll
        for (int off = 32; off > 0; off >>= 1)
            v += __shfl_down(v, off, 64);
        if (lane == 0) partial[q][wid] = v;
    }
    __syncthreads();
    if (tid < 32) {
        float v = partial[tid][0] + partial[tid][1] + partial[tid][2] + partial[tid][3] + bm2[0];
        out[q0 + tid] = fmaxf(v, 0.f);
    }
}

// ---------------- launch ----------------

extern "C" void kernel_launch(void* const* d_in, const int* in_sizes, int n_in,
                              void* d_out, int out_size, void* d_ws, size_t ws_size,
                              hipStream_t stream) {
    const float* x    = (const float*)d_in[0];
    const int*   ei   = (const int*)d_in[1];
    const int*   qry  = (const int*)d_in[2];
    const float* W1l  = (const float*)d_in[3];
    const float* b1l  = (const float*)d_in[4];
    const float* W1r  = (const float*)d_in[5];
    const float* b1r  = (const float*)d_in[6];
    const float* att1 = (const float*)d_in[7];
    const float* W2l  = (const float*)d_in[8];
    const float* b2l  = (const float*)d_in[9];
    const float* W2r  = (const float*)d_in[10];
    const float* b2r  = (const float*)d_in[11];
    const float* att2 = (const float*)d_in[12];
    const float* Wm1  = (const float*)d_in[13];
    const float* bm1  = (const float*)d_in[14];
    const float* Wm2  = (const float*)d_in[15];
    const float* bm2  = (const float*)d_in[16];
    float* out = (float*)d_out;

    // workspace carve-up
    float* xl    = (float*)d_ws;                 // NN*DD
    float* xr    = xl + (size_t)NN * DD;         // NN*DD
    float* hbuf  = xr + (size_t)NN * DD;         // NN*DD  (h after layer1; reused as emb)
    float* evals = hbuf + (size_t)NN * DD;       // ET
    int* rowptr  = (int*)(evals + ET);           // NN+1
    int* fill    = rowptr + NN + 1;              // NN (also histogram counts)
    int* ssrc    = fill + NN;                    // ET
    int* sdst    = ssrc + ET;                    // ET

    dim3 blk(256);
    int gET = (ET + 255) / 256;

    // ---- CSR build (graph shared by both layers) ----
    hipMemsetAsync(fill, 0, (size_t)NN * sizeof(int), stream);
    count_kernel<<<gET, blk, 0, stream>>>(ei, fill);
    scan_kernel<<<1, 1024, 0, stream>>>(fill, rowptr);
    hipMemsetAsync(fill, 0, (size_t)NN * sizeof(int), stream);
    scatter_kernel<<<gET, blk, 0, stream>>>(ei, rowptr, fill, ssrc, sdst);

    int gRows = (NN + 31) / 32;
    int gEdge = (ET + 3) / 4;
    int gNode = (NN + 3) / 4;

    // ---- layer 1 ----
    {
        int K = FIN, KP = (K + 3) & ~3;
        size_t lds = (size_t)32 * KP * sizeof(float);
        gemm_kernel<<<gRows, blk, lds, stream>>>(x, W1l, b1l, xl, NN, K, DD, 0);
        gemm_kernel<<<gRows, blk, lds, stream>>>(x, W1r, b1r, xr, NN, K, DD, 0);
    }
    edge_score_kernel<<<gEdge, blk, 0, stream>>>(ssrc, sdst, xl, xr, att1, evals);
    softmax_kernel<<<gNode, blk, 0, stream>>>(rowptr, evals);
    aggregate_kernel<<<NN, blk, 0, stream>>>(rowptr, ssrc, evals, xl, hbuf, 1);

    // ---- layer 2 (reads hbuf, writes xl/xr; emb overwrites hbuf after GEMMs done) ----
    {
        int K = DD, KP = (K + 3) & ~3;
        size_t lds = (size_t)32 * KP * sizeof(float);
        gemm_kernel<<<gRows, blk, lds, stream>>>(hbuf, W2l, b2l, xl, NN, K, DD, 0);
        gemm_kernel<<<gRows, blk, lds, stream>>>(hbuf, W2r, b2r, xr, NN, K, DD, 0);
    }
    edge_score_kernel<<<gEdge, blk, 0, stream>>>(ssrc, sdst, xl, xr, att2, evals);
    softmax_kernel<<<gNode, blk, 0, stream>>>(rowptr, evals);
    aggregate_kernel<<<NN, blk, 0, stream>>>(rowptr, ssrc, evals, xl, hbuf, 0);

    // ---- head ----
    head_kernel<<<NQ / 32, blk, 0, stream>>>(qry, hbuf, Wm1, bm1, Wm2, bm2, out);
}

// Round 2
// 1866.900 us; speedup vs baseline: 1.7211x; 1.7211x over previous
//
#include <hip/hip_runtime.h>
#include <math.h>

#define NN 50000
#define NE 800000
#define ET (NE + NN)      // 850000 edges incl self loops
#define FIN 128
#define DD 250
#define HD 256
#define NQ 200000
#define NEG_SLOPE 0.2f

// ---------------- CSR build ----------------

__global__ void count_kernel(const int* __restrict__ ei, int* __restrict__ cnt) {
    int k = blockIdx.x * 256 + threadIdx.x;
    if (k >= ET) return;
    int d = (k < NE) ? ei[NE + k] : (k - NE);
    atomicAdd(&cnt[d], 1);
}

__global__ void scan_kernel(const int* __restrict__ cnt, int* __restrict__ rowptr) {
    __shared__ int buf[1024];
    __shared__ int carry;
    int t = threadIdx.x;
    if (t == 0) carry = 0;
    __syncthreads();
    for (int base = 0; base < NN; base += 1024) {
        int i = base + t;
        int v = (i < NN) ? cnt[i] : 0;
        buf[t] = v;
        __syncthreads();
        for (int off = 1; off < 1024; off <<= 1) {
            int add = (t >= off) ? buf[t - off] : 0;
            __syncthreads();
            buf[t] += add;
            __syncthreads();
        }
        if (i < NN) rowptr[i] = carry + buf[t] - v;   // exclusive
        __syncthreads();
        if (t == 1023) carry += buf[1023];
        __syncthreads();
    }
    if (t == 0) rowptr[NN] = carry;
}

__global__ void scatter_kernel(const int* __restrict__ ei,
                               const int* __restrict__ rowptr,
                               int* __restrict__ fill,
                               int* __restrict__ ssrc, int* __restrict__ sdst) {
    int k = blockIdx.x * 256 + threadIdx.x;
    if (k >= ET) return;
    int s, d;
    if (k < NE) { s = ei[k]; d = ei[NE + k]; }
    else        { s = k - NE; d = k - NE; }
    int pos = rowptr[d] + atomicAdd(&fill[d], 1);
    ssrc[pos] = s;
    sdst[pos] = d;
}

// ---------------- register-tiled fp32 GEMM ----------------
// C[M,N] = A[M,K]@B[K,N] (+bias) ; tile 128x128, 256 threads, 8x8 micro-tile

#define TM 128
#define TN 128
#define KT 8

__global__ __launch_bounds__(256) void gemm_tiled(
    const float* __restrict__ A, const float* __restrict__ B,
    const float* __restrict__ bias, float* __restrict__ C,
    int M, int K, int N, int dorelu)
{
    __shared__ float aT[KT][TM];   // A transposed: aT[k][row]
    __shared__ float bS[KT][TN];   // bS[k][col]
    int row0 = blockIdx.x * TM;
    int col0 = blockIdx.y * TN;
    int t = threadIdx.x;
    int tx = t & 15, ty = t >> 4;

    float acc[8][8];
#pragma unroll
    for (int i = 0; i < 8; i++)
#pragma unroll
        for (int j = 0; j < 8; j++) acc[i][j] = 0.f;

    for (int k0 = 0; k0 < K; k0 += KT) {
        // stage A tile (128 rows x 8 k), transposed into LDS
        {
            int r = t >> 1, kk = (t & 1) * 4;
            int grow = row0 + r;
            float v0 = 0.f, v1 = 0.f, v2 = 0.f, v3 = 0.f;
            if (grow < M) {
                const float* p = &A[(size_t)grow * K + k0 + kk];
                if (k0 + kk + 3 < K) {
                    float4 v = *(const float4*)p;
                    v0 = v.x; v1 = v.y; v2 = v.z; v3 = v.w;
                } else {
                    if (k0 + kk + 0 < K) v0 = p[0];
                    if (k0 + kk + 1 < K) v1 = p[1];
                    if (k0 + kk + 2 < K) v2 = p[2];
                    if (k0 + kk + 3 < K) v3 = p[3];
                }
            }
            aT[kk + 0][r] = v0;
            aT[kk + 1][r] = v1;
            aT[kk + 2][r] = v2;
            aT[kk + 3][r] = v3;
        }
        // stage B tile (8 k x 128 cols)
        {
            int kk = t >> 5, c4 = (t & 31) * 4;
            int gk = k0 + kk;
            float4 v = make_float4(0.f, 0.f, 0.f, 0.f);
            if (gk < K) {
                int gc = col0 + c4;
                const float* p = &B[(size_t)gk * N + gc];
                if (gc + 3 < N) v = *(const float4*)p;
                else {
                    if (gc + 0 < N) v.x = p[0];
                    if (gc + 1 < N) v.y = p[1];
                    if (gc + 2 < N) v.z = p[2];
                    if (gc + 3 < N) v.w = p[3];
                }
            }
            *(float4*)&bS[kk][c4] = v;
        }
        __syncthreads();
#pragma unroll
        for (int kk = 0; kk < KT; kk++) {
            float4 a0 = *(const float4*)&aT[kk][ty * 8];
            float4 a1 = *(const float4*)&aT[kk][ty * 8 + 4];
            float4 b0 = *(const float4*)&bS[kk][tx * 8];
            float4 b1 = *(const float4*)&bS[kk][tx * 8 + 4];
            float ar[8] = {a0.x, a0.y, a0.z, a0.w, a1.x, a1.y, a1.z, a1.w};
            float br[8] = {b0.x, b0.y, b0.z, b0.w, b1.x, b1.y, b1.z, b1.w};
#pragma unroll
            for (int i = 0; i < 8; i++)
#pragma unroll
                for (int j = 0; j < 8; j++) acc[i][j] += ar[i] * br[j];
        }
        __syncthreads();
    }

    // epilogue
#pragma unroll
    for (int i = 0; i < 8; i++) {
        int gr = row0 + ty * 8 + i;
        if (gr >= M) continue;
#pragma unroll
        for (int j = 0; j < 8; j++) {
            int gc = col0 + tx * 8 + j;
            if (gc < N) {
                float v = acc[i][j] + (bias ? bias[gc] : 0.f);
                if (dorelu) v = fmaxf(v, 0.f);
                C[(size_t)gr * N + gc] = v;
            }
        }
    }
}

// ---------------- edge score: e_k = att . leaky_relu(xl[src]+xr[dst]) ----------------

__global__ __launch_bounds__(256) void edge_score_kernel(
    const int* __restrict__ ssrc, const int* __restrict__ sdst,
    const float* __restrict__ xl, const float* __restrict__ xr,
    const float* __restrict__ att, float* __restrict__ e)
{
    int k = blockIdx.x * 4 + (threadIdx.x >> 6);
    if (k >= ET) return;
    int lane = threadIdx.x & 63;
    int s = ssrc[k], dd = sdst[k];
    const float* pl = xl + (size_t)s * DD;
    const float* pr = xr + (size_t)dd * DD;
    float p = 0.f;
    for (int d = lane; d < DD; d += 64) {
        float v = pl[d] + pr[d];
        v = (v > 0.f) ? v : NEG_SLOPE * v;
        p += att[d] * v;
    }
#pragma unroll
    for (int off = 32; off > 0; off >>= 1)
        p += __shfl_down(p, off, 64);
    if (lane == 0) e[k] = p;
}

// ---------------- per-dst softmax ----------------

__global__ __launch_bounds__(256) void softmax_kernel(
    const int* __restrict__ rowptr, float* __restrict__ e)
{
    int i = blockIdx.x * 4 + (threadIdx.x >> 6);
    if (i >= NN) return;
    int lane = threadIdx.x & 63;
    int beg = rowptr[i], end = rowptr[i + 1];
    float m = -1e30f;
    for (int p = beg + lane; p < end; p += 64) m = fmaxf(m, e[p]);
#pragma unroll
    for (int off = 32; off > 0; off >>= 1)
        m = fmaxf(m, __shfl_xor(m, off, 64));
    float ssum = 0.f;
    for (int p = beg + lane; p < end; p += 64) ssum += expf(e[p] - m);
#pragma unroll
    for (int off = 32; off > 0; off >>= 1)
        ssum += __shfl_xor(ssum, off, 64);
    float inv = 1.f / ssum;
    for (int p = beg + lane; p < end; p += 64) e[p] = expf(e[p] - m) * inv;
}

// ---------------- aggregation ----------------

__global__ __launch_bounds__(256) void aggregate_kernel(
    const int* __restrict__ rowptr, const int* __restrict__ ssrc,
    const float* __restrict__ alpha, const float* __restrict__ xl,
    float* __restrict__ out, int dorelu)
{
    int i = blockIdx.x;
    int t = threadIdx.x;
    int beg = rowptr[i], end = rowptr[i + 1];
    float acc = 0.f;
    for (int p = beg; p < end; p++) {
        int s = ssrc[p];
        float a = alpha[p];
        if (t < DD) acc += a * xl[(size_t)s * DD + t];
    }
    if (t < DD) {
        if (dorelu) acc = fmaxf(acc, 0.f);
        out[(size_t)i * DD + t] = acc;
    }
}

// ---------------- query head: out[q] = relu( relu(Ptop[a]+Pbot[b]) . Wm2 + bm2 ) ----------------
// one wave per query; 256 hidden units = 64 lanes x float4

__global__ __launch_bounds__(256) void query_kernel(
    const int* __restrict__ qry, const float* __restrict__ Ptop,
    const float* __restrict__ Pbot, const float* __restrict__ Wm2,
    const float* __restrict__ bm2, float* __restrict__ out)
{
    int q = blockIdx.x * 4 + (threadIdx.x >> 6);
    if (q >= NQ) return;
    int lane = threadIdx.x & 63;
    int a = qry[q * 2 + 0], b = qry[q * 2 + 1];
    float4 tv = *(const float4*)&Ptop[(size_t)a * HD + lane * 4];
    float4 bv = *(const float4*)&Pbot[(size_t)b * HD + lane * 4];
    float4 w  = *(const float4*)&Wm2[lane * 4];
    float s = fmaxf(tv.x + bv.x, 0.f) * w.x
            + fmaxf(tv.y + bv.y, 0.f) * w.y
            + fmaxf(tv.z + bv.z, 0.f) * w.z
            + fmaxf(tv.w + bv.w, 0.f) * w.w;
#pragma unroll
    for (int off = 32; off > 0; off >>= 1)
        s += __shfl_down(s, off, 64);
    if (lane == 0) out[q] = fmaxf(s + bm2[0], 0.f);
}

// ---------------- launch ----------------

extern "C" void kernel_launch(void* const* d_in, const int* in_sizes, int n_in,
                              void* d_out, int out_size, void* d_ws, size_t ws_size,
                              hipStream_t stream) {
    const float* x    = (const float*)d_in[0];
    const int*   ei   = (const int*)d_in[1];
    const int*   qry  = (const int*)d_in[2];
    const float* W1l  = (const float*)d_in[3];
    const float* b1l  = (const float*)d_in[4];
    const float* W1r  = (const float*)d_in[5];
    const float* b1r  = (const float*)d_in[6];
    const float* att1 = (const float*)d_in[7];
    const float* W2l  = (const float*)d_in[8];
    const float* b2l  = (const float*)d_in[9];
    const float* W2r  = (const float*)d_in[10];
    const float* b2r  = (const float*)d_in[11];
    const float* att2 = (const float*)d_in[12];
    const float* Wm1  = (const float*)d_in[13];
    const float* bm1  = (const float*)d_in[14];
    const float* Wm2  = (const float*)d_in[15];
    const float* bm2  = (const float*)d_in[16];
    float* out = (float*)d_out;

    // workspace carve-up (floats)
    const size_t NND = (size_t)NN * DD;          // 12.5M
    float* hbuf  = (float*)d_ws;                 // [0, NND)
    float* xl    = hbuf + NND;                   // [NND, 2*NND)
    float* xr    = xl + NND;                     // [2*NND, 3*NND)
    float* evals = xr + NND;                     // [3*NND, 3*NND+ET)
    int* rowptr  = (int*)(evals + ET);           // NN+1
    int* fill    = rowptr + NN + 1;              // NN
    int* ssrc    = fill + NN;                    // ET
    int* sdst    = ssrc + ET;                    // ET
    // head precompute buffers overlay xl/xr/evals (free by the time they're written)
    float* Ptop  = xl;                           // NN*HD = 12.8M
    float* Pbot  = xl + (size_t)NN * HD;         // ends at 2*NND + ~0.9M  (< 3*NND+ET)

    dim3 blk(256);
    int gET = (ET + 255) / 256;

    // ---- CSR build (graph shared by both layers) ----
    hipMemsetAsync(fill, 0, (size_t)NN * sizeof(int), stream);
    count_kernel<<<gET, blk, 0, stream>>>(ei, fill);
    scan_kernel<<<1, 1024, 0, stream>>>(fill, rowptr);
    hipMemsetAsync(fill, 0, (size_t)NN * sizeof(int), stream);
    scatter_kernel<<<gET, blk, 0, stream>>>(ei, rowptr, fill, ssrc, sdst);

    int gEdge = (ET + 3) / 4;
    int gNode = (NN + 3) / 4;
    dim3 gemmGridD((NN + TM - 1) / TM, (DD + TN - 1) / TN);   // 391 x 2
    dim3 gemmGridH((NN + TM - 1) / TM, (HD + TN - 1) / TN);   // 391 x 2

    // ---- layer 1 ----
    gemm_tiled<<<gemmGridD, blk, 0, stream>>>(x, W1l, b1l, xl, NN, FIN, DD, 0);
    gemm_tiled<<<gemmGridD, blk, 0, stream>>>(x, W1r, b1r, xr, NN, FIN, DD, 0);
    edge_score_kernel<<<gEdge, blk, 0, stream>>>(ssrc, sdst, xl, xr, att1, evals);
    softmax_kernel<<<gNode, blk, 0, stream>>>(rowptr, evals);
    aggregate_kernel<<<NN, blk, 0, stream>>>(rowptr, ssrc, evals, xl, hbuf, 1);

    // ---- layer 2 ----
    gemm_tiled<<<gemmGridD, blk, 0, stream>>>(hbuf, W2l, b2l, xl, NN, DD, DD, 0);
    gemm_tiled<<<gemmGridD, blk, 0, stream>>>(hbuf, W2r, b2r, xr, NN, DD, DD, 0);
    edge_score_kernel<<<gEdge, blk, 0, stream>>>(ssrc, sdst, xl, xr, att2, evals);
    softmax_kernel<<<gNode, blk, 0, stream>>>(rowptr, evals);
    aggregate_kernel<<<NN, blk, 0, stream>>>(rowptr, ssrc, evals, xl, hbuf, 0);
    // hbuf now holds emb [NN, DD]

    // ---- head precompute: Ptop = emb@Wm1[0:250,:] + bm1 ; Pbot = emb@Wm1[250:500,:] ----
    gemm_tiled<<<gemmGridH, blk, 0, stream>>>(hbuf, Wm1, bm1, Ptop, NN, DD, HD, 0);
    gemm_tiled<<<gemmGridH, blk, 0, stream>>>(hbuf, Wm1 + (size_t)DD * HD, (const float*)nullptr, Pbot, NN, DD, HD, 0);

    // ---- per-query head ----
    query_kernel<<<(NQ + 3) / 4, blk, 0, stream>>>(qry, Ptop, Pbot, Wm2, bm2, out);
}

// Round 3
// 1622.212 us; speedup vs baseline: 1.9807x; 1.1508x over previous
//
#include <hip/hip_runtime.h>
#include <math.h>

#define NN 50000
#define NE 800000
#define ET (NE + NN)      // 850000 edges incl self loops
#define FIN 128
#define DD 250
#define HD 256
#define NQ 200000
#define NEG_SLOPE 0.2f

// ---------------- CSR build ----------------

__global__ void count_kernel(const int* __restrict__ ei, int* __restrict__ cnt) {
    int k = blockIdx.x * 256 + threadIdx.x;
    if (k >= ET) return;
    int d = (k < NE) ? ei[NE + k] : (k - NE);
    atomicAdd(&cnt[d], 1);
}

__global__ void scan_kernel(const int* __restrict__ cnt, int* __restrict__ rowptr) {
    __shared__ int buf[1024];
    __shared__ int carry;
    int t = threadIdx.x;
    if (t == 0) carry = 0;
    __syncthreads();
    for (int base = 0; base < NN; base += 1024) {
        int i = base + t;
        int v = (i < NN) ? cnt[i] : 0;
        buf[t] = v;
        __syncthreads();
        for (int off = 1; off < 1024; off <<= 1) {
            int add = (t >= off) ? buf[t - off] : 0;
            __syncthreads();
            buf[t] += add;
            __syncthreads();
        }
        if (i < NN) rowptr[i] = carry + buf[t] - v;   // exclusive
        __syncthreads();
        if (t == 1023) carry += buf[1023];
        __syncthreads();
    }
    if (t == 0) rowptr[NN] = carry;
}

__global__ void scatter_kernel(const int* __restrict__ ei,
                               const int* __restrict__ rowptr,
                               int* __restrict__ fill,
                               int* __restrict__ ssrc) {
    int k = blockIdx.x * 256 + threadIdx.x;
    if (k >= ET) return;
    int s, d;
    if (k < NE) { s = ei[k]; d = ei[NE + k]; }
    else        { s = k - NE; d = k - NE; }
    int pos = rowptr[d] + atomicAdd(&fill[d], 1);
    ssrc[pos] = s;
}

// ---------------- register-tiled fp32 GEMM ----------------
// C[M,N] = A[M,K]@B[K,N] (+bias) ; tile 128x128, 256 threads, 8x8 micro-tile

#define TM 128
#define TN 128
#define KT 8

__global__ __launch_bounds__(256) void gemm_tiled(
    const float* __restrict__ A, const float* __restrict__ B,
    const float* __restrict__ bias, float* __restrict__ C,
    int M, int K, int N, int dorelu)
{
    __shared__ float aT[KT][TM];   // A transposed: aT[k][row]
    __shared__ float bS[KT][TN];   // bS[k][col]
    int row0 = blockIdx.x * TM;
    int col0 = blockIdx.y * TN;
    int t = threadIdx.x;
    int tx = t & 15, ty = t >> 4;

    float acc[8][8];
#pragma unroll
    for (int i = 0; i < 8; i++)
#pragma unroll
        for (int j = 0; j < 8; j++) acc[i][j] = 0.f;

    for (int k0 = 0; k0 < K; k0 += KT) {
        // stage A tile (128 rows x 8 k), transposed into LDS
        {
            int r = t >> 1, kk = (t & 1) * 4;
            int grow = row0 + r;
            float v0 = 0.f, v1 = 0.f, v2 = 0.f, v3 = 0.f;
            if (grow < M) {
                const float* p = &A[(size_t)grow * K + k0 + kk];
                if (k0 + kk + 3 < K) {
                    float4 v = *(const float4*)p;
                    v0 = v.x; v1 = v.y; v2 = v.z; v3 = v.w;
                } else {
                    if (k0 + kk + 0 < K) v0 = p[0];
                    if (k0 + kk + 1 < K) v1 = p[1];
                    if (k0 + kk + 2 < K) v2 = p[2];
                    if (k0 + kk + 3 < K) v3 = p[3];
                }
            }
            aT[kk + 0][r] = v0;
            aT[kk + 1][r] = v1;
            aT[kk + 2][r] = v2;
            aT[kk + 3][r] = v3;
        }
        // stage B tile (8 k x 128 cols)
        {
            int kk = t >> 5, c4 = (t & 31) * 4;
            int gk = k0 + kk;
            float4 v = make_float4(0.f, 0.f, 0.f, 0.f);
            if (gk < K) {
                int gc = col0 + c4;
                const float* p = &B[(size_t)gk * N + gc];
                if (gc + 3 < N) v = *(const float4*)p;
                else {
                    if (gc + 0 < N) v.x = p[0];
                    if (gc + 1 < N) v.y = p[1];
                    if (gc + 2 < N) v.z = p[2];
                    if (gc + 3 < N) v.w = p[3];
                }
            }
            *(float4*)&bS[kk][c4] = v;
        }
        __syncthreads();
#pragma unroll
        for (int kk = 0; kk < KT; kk++) {
            float4 a0 = *(const float4*)&aT[kk][ty * 8];
            float4 a1 = *(const float4*)&aT[kk][ty * 8 + 4];
            float4 b0 = *(const float4*)&bS[kk][tx * 8];
            float4 b1 = *(const float4*)&bS[kk][tx * 8 + 4];
            float ar[8] = {a0.x, a0.y, a0.z, a0.w, a1.x, a1.y, a1.z, a1.w};
            float br[8] = {b0.x, b0.y, b0.z, b0.w, b1.x, b1.y, b1.z, b1.w};
#pragma unroll
            for (int i = 0; i < 8; i++)
#pragma unroll
                for (int j = 0; j < 8; j++) acc[i][j] += ar[i] * br[j];
        }
        __syncthreads();
    }

    // epilogue
#pragma unroll
    for (int i = 0; i < 8; i++) {
        int gr = row0 + ty * 8 + i;
        if (gr >= M) continue;
#pragma unroll
        for (int j = 0; j < 8; j++) {
            int gc = col0 + tx * 8 + j;
            if (gc < N) {
                float v = acc[i][j] + (bias ? bias[gc] : 0.f);
                if (dorelu) v = fmaxf(v, 0.f);
                C[(size_t)gr * N + gc] = v;
            }
        }
    }
}

// ---------------- fused edge phase: score + softmax + aggregate, one wave per dst node ----------------
// pass 1: online-softmax (m, sum) over e_k = att . leaky_relu(xl[src]+xr[i])
// pass 2: recompute e_k (xl row is L1/L2-hot), alpha = exp(e-m)/sum, acc += alpha*xl[src]

__global__ __launch_bounds__(256) void fused_edge_kernel(
    const int* __restrict__ rowptr, const int* __restrict__ ssrc,
    const float* __restrict__ xl, const float* __restrict__ xr,
    const float* __restrict__ att, float* __restrict__ out, int dorelu)
{
    int i = blockIdx.x * 4 + (threadIdx.x >> 6);
    if (i >= NN) return;
    int lane = threadIdx.x & 63;
    int beg = rowptr[i], end = rowptr[i + 1];
    int d0 = lane * 4;
    bool full = (d0 + 3 < DD);     // lanes 0..61
    bool half = (!full && d0 < DD); // lane 62 -> 2 elems

    float4 xrv = make_float4(0.f, 0.f, 0.f, 0.f);
    float4 atv = make_float4(0.f, 0.f, 0.f, 0.f);
    if (full) {
        xrv = *(const float4*)&xr[(size_t)i * DD + d0];
        atv = *(const float4*)&att[d0];
    } else if (half) {
        xrv.x = xr[(size_t)i * DD + d0];     xrv.y = xr[(size_t)i * DD + d0 + 1];
        atv.x = att[d0];                     atv.y = att[d0 + 1];
    }

    // pass 1: online softmax
    float m = -1e30f, ssum = 0.f;
    for (int p = beg; p < end; p++) {
        int s = ssrc[p];
        float4 xv = make_float4(0.f, 0.f, 0.f, 0.f);
        if (full)      xv = *(const float4*)&xl[(size_t)s * DD + d0];
        else if (half) { xv.x = xl[(size_t)s * DD + d0]; xv.y = xl[(size_t)s * DD + d0 + 1]; }
        float vx = xv.x + xrv.x; vx = (vx > 0.f) ? vx : NEG_SLOPE * vx;
        float vy = xv.y + xrv.y; vy = (vy > 0.f) ? vy : NEG_SLOPE * vy;
        float vz = xv.z + xrv.z; vz = (vz > 0.f) ? vz : NEG_SLOPE * vz;
        float vw = xv.w + xrv.w; vw = (vw > 0.f) ? vw : NEG_SLOPE * vw;
        float e = vx * atv.x + vy * atv.y + vz * atv.z + vw * atv.w;
#pragma unroll
        for (int off = 1; off < 64; off <<= 1)
            e += __shfl_xor(e, off, 64);
        float nm = fmaxf(m, e);
        ssum = ssum * expf(m - nm) + expf(e - nm);
        m = nm;
    }
    float inv = 1.f / ssum;

    // pass 2: aggregate
    float4 acc = make_float4(0.f, 0.f, 0.f, 0.f);
    for (int p = beg; p < end; p++) {
        int s = ssrc[p];
        float4 xv = make_float4(0.f, 0.f, 0.f, 0.f);
        if (full)      xv = *(const float4*)&xl[(size_t)s * DD + d0];
        else if (half) { xv.x = xl[(size_t)s * DD + d0]; xv.y = xl[(size_t)s * DD + d0 + 1]; }
        float vx = xv.x + xrv.x; vx = (vx > 0.f) ? vx : NEG_SLOPE * vx;
        float vy = xv.y + xrv.y; vy = (vy > 0.f) ? vy : NEG_SLOPE * vy;
        float vz = xv.z + xrv.z; vz = (vz > 0.f) ? vz : NEG_SLOPE * vz;
        float vw = xv.w + xrv.w; vw = (vw > 0.f) ? vw : NEG_SLOPE * vw;
        float e = vx * atv.x + vy * atv.y + vz * atv.z + vw * atv.w;
#pragma unroll
        for (int off = 1; off < 64; off <<= 1)
            e += __shfl_xor(e, off, 64);
        float alpha = expf(e - m) * inv;
        acc.x += alpha * xv.x;
        acc.y += alpha * xv.y;
        acc.z += alpha * xv.z;
        acc.w += alpha * xv.w;
    }
    if (dorelu) {
        acc.x = fmaxf(acc.x, 0.f); acc.y = fmaxf(acc.y, 0.f);
        acc.z = fmaxf(acc.z, 0.f); acc.w = fmaxf(acc.w, 0.f);
    }
    if (full) {
        *(float4*)&out[(size_t)i * DD + d0] = acc;
    } else if (half) {
        out[(size_t)i * DD + d0]     = acc.x;
        out[(size_t)i * DD + d0 + 1] = acc.y;
    }
}

// ---------------- query head: out[q] = relu( relu(Ptop[a]+Pbot[b]) . Wm2 + bm2 ) ----------------

__global__ __launch_bounds__(256) void query_kernel(
    const int* __restrict__ qry, const float* __restrict__ Ptop,
    const float* __restrict__ Pbot, const float* __restrict__ Wm2,
    const float* __restrict__ bm2, float* __restrict__ out)
{
    int q = blockIdx.x * 4 + (threadIdx.x >> 6);
    if (q >= NQ) return;
    int lane = threadIdx.x & 63;
    int a = qry[q * 2 + 0], b = qry[q * 2 + 1];
    float4 tv = *(const float4*)&Ptop[(size_t)a * HD + lane * 4];
    float4 bv = *(const float4*)&Pbot[(size_t)b * HD + lane * 4];
    float4 w  = *(const float4*)&Wm2[lane * 4];
    float s = fmaxf(tv.x + bv.x, 0.f) * w.x
            + fmaxf(tv.y + bv.y, 0.f) * w.y
            + fmaxf(tv.z + bv.z, 0.f) * w.z
            + fmaxf(tv.w + bv.w, 0.f) * w.w;
#pragma unroll
    for (int off = 32; off > 0; off >>= 1)
        s += __shfl_down(s, off, 64);
    if (lane == 0) out[q] = fmaxf(s + bm2[0], 0.f);
}

// ---------------- launch ----------------

extern "C" void kernel_launch(void* const* d_in, const int* in_sizes, int n_in,
                              void* d_out, int out_size, void* d_ws, size_t ws_size,
                              hipStream_t stream) {
    const float* x    = (const float*)d_in[0];
    const int*   ei   = (const int*)d_in[1];
    const int*   qry  = (const int*)d_in[2];
    const float* W1l  = (const float*)d_in[3];
    const float* b1l  = (const float*)d_in[4];
    const float* W1r  = (const float*)d_in[5];
    const float* b1r  = (const float*)d_in[6];
    const float* att1 = (const float*)d_in[7];
    const float* W2l  = (const float*)d_in[8];
    const float* b2l  = (const float*)d_in[9];
    const float* W2r  = (const float*)d_in[10];
    const float* b2r  = (const float*)d_in[11];
    const float* att2 = (const float*)d_in[12];
    const float* Wm1  = (const float*)d_in[13];
    const float* bm1  = (const float*)d_in[14];
    const float* Wm2  = (const float*)d_in[15];
    const float* bm2  = (const float*)d_in[16];
    float* out = (float*)d_out;

    // workspace carve-up (floats)
    const size_t NND = (size_t)NN * DD;          // 12.5M
    float* hbuf  = (float*)d_ws;                 // [0, NND)
    float* xl    = hbuf + NND;                   // [NND, 2*NND)
    float* xr    = xl + NND;                     // [2*NND, 3*NND)
    int* rowptr  = (int*)(xr + NND);             // NN+1
    int* fill    = rowptr + NN + 1;              // NN
    int* ssrc    = fill + NN;                    // ET
    // head precompute buffers overlay xl/xr (free by the time they're written)
    float* Ptop  = xl;                           // NN*HD = 12.8M
    float* Pbot  = xl + (size_t)NN * HD;

    dim3 blk(256);
    int gET = (ET + 255) / 256;

    // ---- CSR build (graph shared by both layers) ----
    hipMemsetAsync(fill, 0, (size_t)NN * sizeof(int), stream);
    count_kernel<<<gET, blk, 0, stream>>>(ei, fill);
    scan_kernel<<<1, 1024, 0, stream>>>(fill, rowptr);
    hipMemsetAsync(fill, 0, (size_t)NN * sizeof(int), stream);
    scatter_kernel<<<gET, blk, 0, stream>>>(ei, rowptr, fill, ssrc);

    int gNode = (NN + 3) / 4;
    dim3 gemmGridD((NN + TM - 1) / TM, (DD + TN - 1) / TN);   // 391 x 2
    dim3 gemmGridH((NN + TM - 1) / TM, (HD + TN - 1) / TN);   // 391 x 2

    // ---- layer 1 ----
    gemm_tiled<<<gemmGridD, blk, 0, stream>>>(x, W1l, b1l, xl, NN, FIN, DD, 0);
    gemm_tiled<<<gemmGridD, blk, 0, stream>>>(x, W1r, b1r, xr, NN, FIN, DD, 0);
    fused_edge_kernel<<<gNode, blk, 0, stream>>>(rowptr, ssrc, xl, xr, att1, hbuf, 1);

    // ---- layer 2 ----
    gemm_tiled<<<gemmGridD, blk, 0, stream>>>(hbuf, W2l, b2l, xl, NN, DD, DD, 0);
    gemm_tiled<<<gemmGridD, blk, 0, stream>>>(hbuf, W2r, b2r, xr, NN, DD, DD, 0);
    fused_edge_kernel<<<gNode, blk, 0, stream>>>(rowptr, ssrc, xl, xr, att2, hbuf, 0);
    // hbuf now holds emb [NN, DD]

    // ---- head precompute: Ptop = emb@Wm1[0:250,:] + bm1 ; Pbot = emb@Wm1[250:500,:] ----
    gemm_tiled<<<gemmGridH, blk, 0, stream>>>(hbuf, Wm1, bm1, Ptop, NN, DD, HD, 0);
    gemm_tiled<<<gemmGridH, blk, 0, stream>>>(hbuf, Wm1 + (size_t)DD * HD, (const float*)nullptr, Pbot, NN, DD, HD, 0);

    // ---- per-query head ----
    query_kernel<<<(NQ + 3) / 4, blk, 0, stream>>>(qry, Ptop, Pbot, Wm2, bm2, out);
}

// Round 4
// 1250.395 us; speedup vs baseline: 2.5696x; 1.2974x over previous
//
#include <hip/hip_runtime.h>
#include <math.h>

#define NN 50000
#define NE 800000
#define ET (NE + NN)      // 850000 edges incl self loops
#define FIN 128
#define DD 250
#define HD 256
#define NQ 200000
#define NEG_SLOPE 0.2f

// ---------------- CSR build ----------------

__global__ void count_kernel(const int* __restrict__ ei, int* __restrict__ cnt) {
    int k = blockIdx.x * 256 + threadIdx.x;
    if (k >= ET) return;
    int d = (k < NE) ? ei[NE + k] : (k - NE);
    atomicAdd(&cnt[d], 1);
}

__global__ void scan_kernel(const int* __restrict__ cnt, int* __restrict__ rowptr) {
    __shared__ int buf[1024];
    __shared__ int carry;
    int t = threadIdx.x;
    if (t == 0) carry = 0;
    __syncthreads();
    for (int base = 0; base < NN; base += 1024) {
        int i = base + t;
        int v = (i < NN) ? cnt[i] : 0;
        buf[t] = v;
        __syncthreads();
        for (int off = 1; off < 1024; off <<= 1) {
            int add = (t >= off) ? buf[t - off] : 0;
            __syncthreads();
            buf[t] += add;
            __syncthreads();
        }
        if (i < NN) rowptr[i] = carry + buf[t] - v;   // exclusive
        __syncthreads();
        if (t == 1023) carry += buf[1023];
        __syncthreads();
    }
    if (t == 0) rowptr[NN] = carry;
}

__global__ void scatter_kernel(const int* __restrict__ ei,
                               const int* __restrict__ rowptr,
                               int* __restrict__ fill,
                               int* __restrict__ ssrc) {
    int k = blockIdx.x * 256 + threadIdx.x;
    if (k >= ET) return;
    int s, d;
    if (k < NE) { s = ei[k]; d = ei[NE + k]; }
    else        { s = k - NE; d = k - NE; }
    int pos = rowptr[d] + atomicAdd(&fill[d], 1);
    ssrc[pos] = s;
}

// ---------------- register-tiled fp32 GEMM ----------------
// C[M,N] = A[M,K]@B[K,N] (+bias) ; tile 128x128, 256 threads, 8x8 micro-tile

#define TM 128
#define TN 128
#define KT 8

__global__ __launch_bounds__(256) void gemm_tiled(
    const float* __restrict__ A, const float* __restrict__ B,
    const float* __restrict__ bias, float* __restrict__ C,
    int M, int K, int N, int dorelu)
{
    __shared__ float aT[KT][TM];   // A transposed: aT[k][row]
    __shared__ float bS[KT][TN];   // bS[k][col]
    int row0 = blockIdx.x * TM;
    int col0 = blockIdx.y * TN;
    int t = threadIdx.x;
    int tx = t & 15, ty = t >> 4;

    float acc[8][8];
#pragma unroll
    for (int i = 0; i < 8; i++)
#pragma unroll
        for (int j = 0; j < 8; j++) acc[i][j] = 0.f;

    for (int k0 = 0; k0 < K; k0 += KT) {
        // stage A tile (128 rows x 8 k), transposed into LDS
        {
            int r = t >> 1, kk = (t & 1) * 4;
            int grow = row0 + r;
            float v0 = 0.f, v1 = 0.f, v2 = 0.f, v3 = 0.f;
            if (grow < M) {
                const float* p = &A[(size_t)grow * K + k0 + kk];
                if (k0 + kk + 3 < K) {
                    float4 v = *(const float4*)p;
                    v0 = v.x; v1 = v.y; v2 = v.z; v3 = v.w;
                } else {
                    if (k0 + kk + 0 < K) v0 = p[0];
                    if (k0 + kk + 1 < K) v1 = p[1];
                    if (k0 + kk + 2 < K) v2 = p[2];
                    if (k0 + kk + 3 < K) v3 = p[3];
                }
            }
            aT[kk + 0][r] = v0;
            aT[kk + 1][r] = v1;
            aT[kk + 2][r] = v2;
            aT[kk + 3][r] = v3;
        }
        // stage B tile (8 k x 128 cols)
        {
            int kk = t >> 5, c4 = (t & 31) * 4;
            int gk = k0 + kk;
            float4 v = make_float4(0.f, 0.f, 0.f, 0.f);
            if (gk < K) {
                int gc = col0 + c4;
                const float* p = &B[(size_t)gk * N + gc];
                if (gc + 3 < N) v = *(const float4*)p;
                else {
                    if (gc + 0 < N) v.x = p[0];
                    if (gc + 1 < N) v.y = p[1];
                    if (gc + 2 < N) v.z = p[2];
                    if (gc + 3 < N) v.w = p[3];
                }
            }
            *(float4*)&bS[kk][c4] = v;
        }
        __syncthreads();
#pragma unroll
        for (int kk = 0; kk < KT; kk++) {
            float4 a0 = *(const float4*)&aT[kk][ty * 8];
            float4 a1 = *(const float4*)&aT[kk][ty * 8 + 4];
            float4 b0 = *(const float4*)&bS[kk][tx * 8];
            float4 b1 = *(const float4*)&bS[kk][tx * 8 + 4];
            float ar[8] = {a0.x, a0.y, a0.z, a0.w, a1.x, a1.y, a1.z, a1.w};
            float br[8] = {b0.x, b0.y, b0.z, b0.w, b1.x, b1.y, b1.z, b1.w};
#pragma unroll
            for (int i = 0; i < 8; i++)
#pragma unroll
                for (int j = 0; j < 8; j++) acc[i][j] += ar[i] * br[j];
        }
        __syncthreads();
    }

    // epilogue
#pragma unroll
    for (int i = 0; i < 8; i++) {
        int gr = row0 + ty * 8 + i;
        if (gr >= M) continue;
#pragma unroll
        for (int j = 0; j < 8; j++) {
            int gc = col0 + tx * 8 + j;
            if (gc < N) {
                float v = acc[i][j] + (bias ? bias[gc] : 0.f);
                if (dorelu) v = fmaxf(v, 0.f);
                C[(size_t)gr * N + gc] = v;
            }
        }
    }
}

// ---------------- fused edge phase: single-pass online softmax + aggregate ----------------
// one wave per dst node; acc rescaled flash-style; 4-edge unroll for MLP

__device__ __forceinline__ float edge_e(float4 xv, float4 xrv, float4 atv) {
    float vx = xv.x + xrv.x; vx = (vx > 0.f) ? vx : NEG_SLOPE * vx;
    float vy = xv.y + xrv.y; vy = (vy > 0.f) ? vy : NEG_SLOPE * vy;
    float vz = xv.z + xrv.z; vz = (vz > 0.f) ? vz : NEG_SLOPE * vz;
    float vw = xv.w + xrv.w; vw = (vw > 0.f) ? vw : NEG_SLOPE * vw;
    return vx * atv.x + vy * atv.y + vz * atv.z + vw * atv.w;
}

__global__ __launch_bounds__(256) void fused_edge_kernel(
    const int* __restrict__ rowptr, const int* __restrict__ ssrc,
    const float* __restrict__ xl, const float* __restrict__ xr,
    const float* __restrict__ att, float* __restrict__ out, int dorelu)
{
    int i = blockIdx.x * 4 + (threadIdx.x >> 6);
    if (i >= NN) return;
    int lane = threadIdx.x & 63;
    int beg = rowptr[i], end = rowptr[i + 1];
    int d0 = lane * 4;
    bool full = (d0 + 3 < DD);      // lanes 0..61
    bool half = (!full && d0 < DD); // lane 62 -> 2 elems

    float4 xrv = make_float4(0.f, 0.f, 0.f, 0.f);
    float4 atv = make_float4(0.f, 0.f, 0.f, 0.f);
    if (full) {
        xrv = *(const float4*)&xr[(size_t)i * DD + d0];
        atv = *(const float4*)&att[d0];
    } else if (half) {
        xrv.x = xr[(size_t)i * DD + d0];     xrv.y = xr[(size_t)i * DD + d0 + 1];
        atv.x = att[d0];                     atv.y = att[d0 + 1];
    }

    float m = -1e30f, ssum = 0.f;
    float4 acc = make_float4(0.f, 0.f, 0.f, 0.f);

    int p = beg;
    for (; p + 3 < end; p += 4) {
        int s0 = ssrc[p], s1 = ssrc[p + 1], s2 = ssrc[p + 2], s3 = ssrc[p + 3];
        float4 x0 = make_float4(0.f, 0.f, 0.f, 0.f);
        float4 x1 = x0, x2 = x0, x3 = x0;
        if (full) {
            x0 = *(const float4*)&xl[(size_t)s0 * DD + d0];
            x1 = *(const float4*)&xl[(size_t)s1 * DD + d0];
            x2 = *(const float4*)&xl[(size_t)s2 * DD + d0];
            x3 = *(const float4*)&xl[(size_t)s3 * DD + d0];
        } else if (half) {
            x0.x = xl[(size_t)s0 * DD + d0]; x0.y = xl[(size_t)s0 * DD + d0 + 1];
            x1.x = xl[(size_t)s1 * DD + d0]; x1.y = xl[(size_t)s1 * DD + d0 + 1];
            x2.x = xl[(size_t)s2 * DD + d0]; x2.y = xl[(size_t)s2 * DD + d0 + 1];
            x3.x = xl[(size_t)s3 * DD + d0]; x3.y = xl[(size_t)s3 * DD + d0 + 1];
        }
        float e0 = edge_e(x0, xrv, atv);
        float e1 = edge_e(x1, xrv, atv);
        float e2 = edge_e(x2, xrv, atv);
        float e3 = edge_e(x3, xrv, atv);
#pragma unroll
        for (int off = 1; off < 64; off <<= 1) {
            e0 += __shfl_xor(e0, off, 64);
            e1 += __shfl_xor(e1, off, 64);
            e2 += __shfl_xor(e2, off, 64);
            e3 += __shfl_xor(e3, off, 64);
        }
        float nm = fmaxf(fmaxf(m, e0), fmaxf(fmaxf(e1, e2), e3));
        float sc = __expf(m - nm);
        float w0 = __expf(e0 - nm);
        float w1 = __expf(e1 - nm);
        float w2 = __expf(e2 - nm);
        float w3 = __expf(e3 - nm);
        acc.x = acc.x * sc + w0 * x0.x + w1 * x1.x + w2 * x2.x + w3 * x3.x;
        acc.y = acc.y * sc + w0 * x0.y + w1 * x1.y + w2 * x2.y + w3 * x3.y;
        acc.z = acc.z * sc + w0 * x0.z + w1 * x1.z + w2 * x2.z + w3 * x3.z;
        acc.w = acc.w * sc + w0 * x0.w + w1 * x1.w + w2 * x2.w + w3 * x3.w;
        ssum = ssum * sc + (w0 + w1) + (w2 + w3);
        m = nm;
    }
    for (; p < end; p++) {
        int s = ssrc[p];
        float4 xv = make_float4(0.f, 0.f, 0.f, 0.f);
        if (full)      xv = *(const float4*)&xl[(size_t)s * DD + d0];
        else if (half) { xv.x = xl[(size_t)s * DD + d0]; xv.y = xl[(size_t)s * DD + d0 + 1]; }
        float e = edge_e(xv, xrv, atv);
#pragma unroll
        for (int off = 1; off < 64; off <<= 1)
            e += __shfl_xor(e, off, 64);
        float nm = fmaxf(m, e);
        float sc = __expf(m - nm);
        float w = __expf(e - nm);
        acc.x = acc.x * sc + w * xv.x;
        acc.y = acc.y * sc + w * xv.y;
        acc.z = acc.z * sc + w * xv.z;
        acc.w = acc.w * sc + w * xv.w;
        ssum = ssum * sc + w;
        m = nm;
    }

    float inv = 1.f / ssum;
    acc.x *= inv; acc.y *= inv; acc.z *= inv; acc.w *= inv;
    if (dorelu) {
        acc.x = fmaxf(acc.x, 0.f); acc.y = fmaxf(acc.y, 0.f);
        acc.z = fmaxf(acc.z, 0.f); acc.w = fmaxf(acc.w, 0.f);
    }
    if (full) {
        *(float4*)&out[(size_t)i * DD + d0] = acc;
    } else if (half) {
        out[(size_t)i * DD + d0]     = acc.x;
        out[(size_t)i * DD + d0 + 1] = acc.y;
    }
}

// ---------------- query head: out[q] = relu( relu(Ptop[a]+Pbot[b]) . Wm2 + bm2 ) ----------------

__global__ __launch_bounds__(256) void query_kernel(
    const int* __restrict__ qry, const float* __restrict__ Ptop,
    const float* __restrict__ Pbot, const float* __restrict__ Wm2,
    const float* __restrict__ bm2, float* __restrict__ out)
{
    int q = blockIdx.x * 4 + (threadIdx.x >> 6);
    if (q >= NQ) return;
    int lane = threadIdx.x & 63;
    int a = qry[q * 2 + 0], b = qry[q * 2 + 1];
    float4 tv = *(const float4*)&Ptop[(size_t)a * HD + lane * 4];
    float4 bv = *(const float4*)&Pbot[(size_t)b * HD + lane * 4];
    float4 w  = *(const float4*)&Wm2[lane * 4];
    float s = fmaxf(tv.x + bv.x, 0.f) * w.x
            + fmaxf(tv.y + bv.y, 0.f) * w.y
            + fmaxf(tv.z + bv.z, 0.f) * w.z
            + fmaxf(tv.w + bv.w, 0.f) * w.w;
#pragma unroll
    for (int off = 32; off > 0; off >>= 1)
        s += __shfl_down(s, off, 64);
    if (lane == 0) out[q] = fmaxf(s + bm2[0], 0.f);
}

// ---------------- launch ----------------

extern "C" void kernel_launch(void* const* d_in, const int* in_sizes, int n_in,
                              void* d_out, int out_size, void* d_ws, size_t ws_size,
                              hipStream_t stream) {
    const float* x    = (const float*)d_in[0];
    const int*   ei   = (const int*)d_in[1];
    const int*   qry  = (const int*)d_in[2];
    const float* W1l  = (const float*)d_in[3];
    const float* b1l  = (const float*)d_in[4];
    const float* W1r  = (const float*)d_in[5];
    const float* b1r  = (const float*)d_in[6];
    const float* att1 = (const float*)d_in[7];
    const float* W2l  = (const float*)d_in[8];
    const float* b2l  = (const float*)d_in[9];
    const float* W2r  = (const float*)d_in[10];
    const float* b2r  = (const float*)d_in[11];
    const float* att2 = (const float*)d_in[12];
    const float* Wm1  = (const float*)d_in[13];
    const float* bm1  = (const float*)d_in[14];
    const float* Wm2  = (const float*)d_in[15];
    const float* bm2  = (const float*)d_in[16];
    float* out = (float*)d_out;

    // workspace carve-up (floats)
    const size_t NND = (size_t)NN * DD;          // 12.5M
    float* hbuf  = (float*)d_ws;                 // [0, NND)
    float* xl    = hbuf + NND;                   // [NND, 2*NND)
    float* xr    = xl + NND;                     // [2*NND, 3*NND)
    int* rowptr  = (int*)(xr + NND);             // NN+1
    int* fill    = rowptr + NN + 1;              // NN
    int* ssrc    = fill + NN;                    // ET
    // head precompute buffers overlay xl/xr (free by the time they're written)
    float* Ptop  = xl;                           // NN*HD = 12.8M
    float* Pbot  = xl + (size_t)NN * HD;

    dim3 blk(256);
    int gET = (ET + 255) / 256;

    // ---- CSR build (graph shared by both layers) ----
    hipMemsetAsync(fill, 0, (size_t)NN * sizeof(int), stream);
    count_kernel<<<gET, blk, 0, stream>>>(ei, fill);
    scan_kernel<<<1, 1024, 0, stream>>>(fill, rowptr);
    hipMemsetAsync(fill, 0, (size_t)NN * sizeof(int), stream);
    scatter_kernel<<<gET, blk, 0, stream>>>(ei, rowptr, fill, ssrc);

    int gNode = (NN + 3) / 4;
    dim3 gemmGridD((NN + TM - 1) / TM, (DD + TN - 1) / TN);   // 391 x 2
    dim3 gemmGridH((NN + TM - 1) / TM, (HD + TN - 1) / TN);   // 391 x 2

    // ---- layer 1 ----
    gemm_tiled<<<gemmGridD, blk, 0, stream>>>(x, W1l, b1l, xl, NN, FIN, DD, 0);
    gemm_tiled<<<gemmGridD, blk, 0, stream>>>(x, W1r, b1r, xr, NN, FIN, DD, 0);
    fused_edge_kernel<<<gNode, blk, 0, stream>>>(rowptr, ssrc, xl, xr, att1, hbuf, 1);

    // ---- layer 2 ----
    gemm_tiled<<<gemmGridD, blk, 0, stream>>>(hbuf, W2l, b2l, xl, NN, DD, DD, 0);
    gemm_tiled<<<gemmGridD, blk, 0, stream>>>(hbuf, W2r, b2r, xr, NN, DD, DD, 0);
    fused_edge_kernel<<<gNode, blk, 0, stream>>>(rowptr, ssrc, xl, xr, att2, hbuf, 0);
    // hbuf now holds emb [NN, DD]

    // ---- head precompute: Ptop = emb@Wm1[0:250,:] + bm1 ; Pbot = emb@Wm1[250:500,:] ----
    gemm_tiled<<<gemmGridH, blk, 0, stream>>>(hbuf, Wm1, bm1, Ptop, NN, DD, HD, 0);
    gemm_tiled<<<gemmGridH, blk, 0, stream>>>(hbuf, Wm1 + (size_t)DD * HD, (const float*)nullptr, Pbot, NN, DD, HD, 0);

    // ---- per-query head ----
    query_kernel<<<(NQ + 3) / 4, blk, 0, stream>>>(qry, Ptop, Pbot, Wm2, bm2, out);
}

// Round 5
// 1000.569 us; speedup vs baseline: 3.2112x; 1.2497x over previous
//
#include <hip/hip_runtime.h>
#include <math.h>

#define NN 50000
#define NE 800000
#define ET (NE + NN)      // 850000 edges incl self loops
#define FIN 128
#define DD 250
#define HD 256
#define NQ 200000
#define NEG_SLOPE 0.2f

typedef __attribute__((ext_vector_type(8))) short bf16x8;
typedef __attribute__((ext_vector_type(4))) float f32x4;

// ---------------- CSR build ----------------

__global__ void count_kernel(const int* __restrict__ ei, int* __restrict__ cnt) {
    int k = blockIdx.x * 256 + threadIdx.x;
    if (k >= ET) return;
    int d = (k < NE) ? ei[NE + k] : (k - NE);
    atomicAdd(&cnt[d], 1);
}

__global__ void scan_kernel(const int* __restrict__ cnt, int* __restrict__ rowptr) {
    __shared__ int buf[1024];
    __shared__ int carry;
    int t = threadIdx.x;
    if (t == 0) carry = 0;
    __syncthreads();
    for (int base = 0; base < NN; base += 1024) {
        int i = base + t;
        int v = (i < NN) ? cnt[i] : 0;
        buf[t] = v;
        __syncthreads();
        for (int off = 1; off < 1024; off <<= 1) {
            int add = (t >= off) ? buf[t - off] : 0;
            __syncthreads();
            buf[t] += add;
            __syncthreads();
        }
        if (i < NN) rowptr[i] = carry + buf[t] - v;   // exclusive
        __syncthreads();
        if (t == 1023) carry += buf[1023];
        __syncthreads();
    }
    if (t == 0) rowptr[NN] = carry;
}

__global__ void scatter_kernel(const int* __restrict__ ei,
                               const int* __restrict__ rowptr,
                               int* __restrict__ fill,
                               int* __restrict__ ssrc) {
    int k = blockIdx.x * 256 + threadIdx.x;
    if (k >= ET) return;
    int s, d;
    if (k < NE) { s = ei[k]; d = ei[NE + k]; }
    else        { s = k - NE; d = k - NE; }
    int pos = rowptr[d] + atomicAdd(&fill[d], 1);
    ssrc[pos] = s;
}

// ---------------- split-bf16 MFMA GEMM ----------------
// C[M,N] = A[M,K]@B[K,N] (+bias); fp32 in/out, internally A=Ah+Al, B=Bh+Bl (bf16),
// acc += Ah*Bh + Ah*Bl + Al*Bh  (fp32 MFMA accumulate; error ~1e-4 rel)
// 128x128 block tile, 4 waves 2x2, wave tile 64x64 = 4x4 frags of 16x16x32.

__device__ __forceinline__ unsigned short f2bf_rne(float x) {
    unsigned int b = __float_as_uint(x);
    unsigned int r = (b + 0x7FFFu + ((b >> 16) & 1u)) >> 16;
    return (unsigned short)r;
}

__global__ __launch_bounds__(256, 2) void gemm_mfma(
    const float* __restrict__ A, const float* __restrict__ B,
    const float* __restrict__ bias, float* __restrict__ C,
    int M, int K, int N)
{
    __shared__ short Ah[128][32];
    __shared__ short Al[128][32];
    __shared__ short Bh[128][32];   // transposed: [n][k]
    __shared__ short Bl[128][32];

    int row0 = blockIdx.x * 128;
    int col0 = blockIdx.y * 128;
    int t = threadIdx.x;
    int lane = t & 63, w = t >> 6;
    int wr = w >> 1, wc = w & 1;
    int quad = lane >> 4, rr = lane & 15;

    f32x4 acc[4][4];
#pragma unroll
    for (int i = 0; i < 4; i++)
#pragma unroll
        for (int j = 0; j < 4; j++) acc[i][j] = (f32x4){0.f, 0.f, 0.f, 0.f};

    // staging indices
    int ar = t >> 1;                 // A row 0..127
    int akh = (t & 1) * 16;          // A k-half
    int bn = t >> 1;                 // B col 0..127
    int bkh = (t & 1) * 16;          // B k-half

    int Kend = (K + 31) & ~31;
    for (int k0 = 0; k0 < Kend; k0 += 32) {
        // ---- stage A [128 x 32] as hi/lo bf16 ----
        {
            bf16x8 h0{}, h1{}, l0{}, l1{};
            int gr = row0 + ar;
            if (gr < M) {
                const float* ap = A + (size_t)gr * K + k0 + akh;
#pragma unroll
                for (int jj = 0; jj < 16; jj += 2) {
                    int kk = k0 + akh + jj;
                    float vx = 0.f, vy = 0.f;
                    if (kk + 1 < K) { float2 v2 = *(const float2*)(ap + jj); vx = v2.x; vy = v2.y; }
                    else if (kk < K) { vx = ap[jj]; }
                    unsigned int bx = __float_as_uint(vx);
                    unsigned int by = __float_as_uint(vy);
                    unsigned short hx = (unsigned short)(bx >> 16);
                    unsigned short hy = (unsigned short)(by >> 16);
                    float rx = vx - __uint_as_float(bx & 0xFFFF0000u);
                    float ry = vy - __uint_as_float(by & 0xFFFF0000u);
                    unsigned short lx = f2bf_rne(rx);
                    unsigned short ly = f2bf_rne(ry);
                    if (jj < 8) { h0[jj] = (short)hx; h0[jj + 1] = (short)hy; l0[jj] = (short)lx; l0[jj + 1] = (short)ly; }
                    else        { h1[jj - 8] = (short)hx; h1[jj - 7] = (short)hy; l1[jj - 8] = (short)lx; l1[jj - 7] = (short)ly; }
                }
            }
            *(bf16x8*)&Ah[ar][akh]     = h0;
            *(bf16x8*)&Ah[ar][akh + 8] = h1;
            *(bf16x8*)&Al[ar][akh]     = l0;
            *(bf16x8*)&Al[ar][akh + 8] = l1;
        }
        // ---- stage B [32 x 128] transposed into [n][k] hi/lo ----
        {
            bf16x8 h0{}, h1{}, l0{}, l1{};
            int gc = col0 + bn;
            if (gc < N) {
#pragma unroll
                for (int jj = 0; jj < 16; jj++) {
                    int kk = k0 + bkh + jj;
                    float v = (kk < K) ? B[(size_t)kk * N + gc] : 0.f;
                    unsigned int b = __float_as_uint(v);
                    unsigned short h = (unsigned short)(b >> 16);
                    float r = v - __uint_as_float(b & 0xFFFF0000u);
                    unsigned short l = f2bf_rne(r);
                    if (jj < 8) { h0[jj] = (short)h; l0[jj] = (short)l; }
                    else        { h1[jj - 8] = (short)h; l1[jj - 8] = (short)l; }
                }
            }
            *(bf16x8*)&Bh[bn][bkh]     = h0;
            *(bf16x8*)&Bh[bn][bkh + 8] = h1;
            *(bf16x8*)&Bl[bn][bkh]     = l0;
            *(bf16x8*)&Bl[bn][bkh + 8] = l1;
        }
        __syncthreads();

        bf16x8 fAh[4], fAl[4], fBh[4], fBl[4];
#pragma unroll
        for (int fi = 0; fi < 4; fi++) {
            int r = wr * 64 + fi * 16 + rr;
            fAh[fi] = *(const bf16x8*)&Ah[r][quad * 8];
            fAl[fi] = *(const bf16x8*)&Al[r][quad * 8];
        }
#pragma unroll
        for (int fj = 0; fj < 4; fj++) {
            int c = wc * 64 + fj * 16 + rr;
            fBh[fj] = *(const bf16x8*)&Bh[c][quad * 8];
            fBl[fj] = *(const bf16x8*)&Bl[c][quad * 8];
        }
#pragma unroll
        for (int fi = 0; fi < 4; fi++)
#pragma unroll
            for (int fj = 0; fj < 4; fj++) {
                acc[fi][fj] = __builtin_amdgcn_mfma_f32_16x16x32_bf16(fAh[fi], fBh[fj], acc[fi][fj], 0, 0, 0);
                acc[fi][fj] = __builtin_amdgcn_mfma_f32_16x16x32_bf16(fAh[fi], fBl[fj], acc[fi][fj], 0, 0, 0);
                acc[fi][fj] = __builtin_amdgcn_mfma_f32_16x16x32_bf16(fAl[fi], fBh[fj], acc[fi][fj], 0, 0, 0);
            }
        __syncthreads();
    }

    // epilogue: C/D layout col=lane&15, row=quad*4+reg
#pragma unroll
    for (int fi = 0; fi < 4; fi++) {
#pragma unroll
        for (int fj = 0; fj < 4; fj++) {
            int gc = col0 + wc * 64 + fj * 16 + rr;
            if (gc >= N) continue;
            float bb = bias ? bias[gc] : 0.f;
#pragma unroll
            for (int r = 0; r < 4; r++) {
                int gr = row0 + wr * 64 + fi * 16 + quad * 4 + r;
                if (gr < M) C[(size_t)gr * N + gc] = acc[fi][fj][r] + bb;
            }
        }
    }
}

// ---------------- fused edge phase: single-pass online softmax + aggregate ----------------

__device__ __forceinline__ float edge_e(float4 xv, float4 xrv, float4 atv) {
    float vx = xv.x + xrv.x; vx = (vx > 0.f) ? vx : NEG_SLOPE * vx;
    float vy = xv.y + xrv.y; vy = (vy > 0.f) ? vy : NEG_SLOPE * vy;
    float vz = xv.z + xrv.z; vz = (vz > 0.f) ? vz : NEG_SLOPE * vz;
    float vw = xv.w + xrv.w; vw = (vw > 0.f) ? vw : NEG_SLOPE * vw;
    return vx * atv.x + vy * atv.y + vz * atv.z + vw * atv.w;
}

__global__ __launch_bounds__(256) void fused_edge_kernel(
    const int* __restrict__ rowptr, const int* __restrict__ ssrc,
    const float* __restrict__ xl, const float* __restrict__ xr,
    const float* __restrict__ att, float* __restrict__ out, int dorelu)
{
    int i = blockIdx.x * 4 + (threadIdx.x >> 6);
    if (i >= NN) return;
    int lane = threadIdx.x & 63;
    int beg = rowptr[i], end = rowptr[i + 1];
    int d0 = lane * 4;
    bool full = (d0 + 3 < DD);      // lanes 0..61
    bool half = (!full && d0 < DD); // lane 62 -> 2 elems

    float4 xrv = make_float4(0.f, 0.f, 0.f, 0.f);
    float4 atv = make_float4(0.f, 0.f, 0.f, 0.f);
    if (full) {
        xrv = *(const float4*)&xr[(size_t)i * DD + d0];
        atv = *(const float4*)&att[d0];
    } else if (half) {
        xrv.x = xr[(size_t)i * DD + d0];     xrv.y = xr[(size_t)i * DD + d0 + 1];
        atv.x = att[d0];                     atv.y = att[d0 + 1];
    }

    float m = -1e30f, ssum = 0.f;
    float4 acc = make_float4(0.f, 0.f, 0.f, 0.f);

    int p = beg;
    for (; p + 3 < end; p += 4) {
        int s0 = ssrc[p], s1 = ssrc[p + 1], s2 = ssrc[p + 2], s3 = ssrc[p + 3];
        float4 x0 = make_float4(0.f, 0.f, 0.f, 0.f);
        float4 x1 = x0, x2 = x0, x3 = x0;
        if (full) {
            x0 = *(const float4*)&xl[(size_t)s0 * DD + d0];
            x1 = *(const float4*)&xl[(size_t)s1 * DD + d0];
            x2 = *(const float4*)&xl[(size_t)s2 * DD + d0];
            x3 = *(const float4*)&xl[(size_t)s3 * DD + d0];
        } else if (half) {
            x0.x = xl[(size_t)s0 * DD + d0]; x0.y = xl[(size_t)s0 * DD + d0 + 1];
            x1.x = xl[(size_t)s1 * DD + d0]; x1.y = xl[(size_t)s1 * DD + d0 + 1];
            x2.x = xl[(size_t)s2 * DD + d0]; x2.y = xl[(size_t)s2 * DD + d0 + 1];
            x3.x = xl[(size_t)s3 * DD + d0]; x3.y = xl[(size_t)s3 * DD + d0 + 1];
        }
        float e0 = edge_e(x0, xrv, atv);
        float e1 = edge_e(x1, xrv, atv);
        float e2 = edge_e(x2, xrv, atv);
        float e3 = edge_e(x3, xrv, atv);
#pragma unroll
        for (int off = 1; off < 64; off <<= 1) {
            e0 += __shfl_xor(e0, off, 64);
            e1 += __shfl_xor(e1, off, 64);
            e2 += __shfl_xor(e2, off, 64);
            e3 += __shfl_xor(e3, off, 64);
        }
        float nm = fmaxf(fmaxf(m, e0), fmaxf(fmaxf(e1, e2), e3));
        float sc = __expf(m - nm);
        float w0 = __expf(e0 - nm);
        float w1 = __expf(e1 - nm);
        float w2 = __expf(e2 - nm);
        float w3 = __expf(e3 - nm);
        acc.x = acc.x * sc + w0 * x0.x + w1 * x1.x + w2 * x2.x + w3 * x3.x;
        acc.y = acc.y * sc + w0 * x0.y + w1 * x1.y + w2 * x2.y + w3 * x3.y;
        acc.z = acc.z * sc + w0 * x0.z + w1 * x1.z + w2 * x2.z + w3 * x3.z;
        acc.w = acc.w * sc + w0 * x0.w + w1 * x1.w + w2 * x2.w + w3 * x3.w;
        ssum = ssum * sc + (w0 + w1) + (w2 + w3);
        m = nm;
    }
    for (; p < end; p++) {
        int s = ssrc[p];
        float4 xv = make_float4(0.f, 0.f, 0.f, 0.f);
        if (full)      xv = *(const float4*)&xl[(size_t)s * DD + d0];
        else if (half) { xv.x = xl[(size_t)s * DD + d0]; xv.y = xl[(size_t)s * DD + d0 + 1]; }
        float e = edge_e(xv, xrv, atv);
#pragma unroll
        for (int off = 1; off < 64; off <<= 1)
            e += __shfl_xor(e, off, 64);
        float nm = fmaxf(m, e);
        float sc = __expf(m - nm);
        float w = __expf(e - nm);
        acc.x = acc.x * sc + w * xv.x;
        acc.y = acc.y * sc + w * xv.y;
        acc.z = acc.z * sc + w * xv.z;
        acc.w = acc.w * sc + w * xv.w;
        ssum = ssum * sc + w;
        m = nm;
    }

    float inv = 1.f / ssum;
    acc.x *= inv; acc.y *= inv; acc.z *= inv; acc.w *= inv;
    if (dorelu) {
        acc.x = fmaxf(acc.x, 0.f); acc.y = fmaxf(acc.y, 0.f);
        acc.z = fmaxf(acc.z, 0.f); acc.w = fmaxf(acc.w, 0.f);
    }
    if (full) {
        *(float4*)&out[(size_t)i * DD + d0] = acc;
    } else if (half) {
        out[(size_t)i * DD + d0]     = acc.x;
        out[(size_t)i * DD + d0 + 1] = acc.y;
    }
}

// ---------------- query head: out[q] = relu( relu(Ptop[a]+Pbot[b]) . Wm2 + bm2 ) ----------------

__global__ __launch_bounds__(256) void query_kernel(
    const int* __restrict__ qry, const float* __restrict__ Ptop,
    const float* __restrict__ Pbot, const float* __restrict__ Wm2,
    const float* __restrict__ bm2, float* __restrict__ out)
{
    int q = blockIdx.x * 4 + (threadIdx.x >> 6);
    if (q >= NQ) return;
    int lane = threadIdx.x & 63;
    int a = qry[q * 2 + 0], b = qry[q * 2 + 1];
    float4 tv = *(const float4*)&Ptop[(size_t)a * HD + lane * 4];
    float4 bv = *(const float4*)&Pbot[(size_t)b * HD + lane * 4];
    float4 w  = *(const float4*)&Wm2[lane * 4];
    float s = fmaxf(tv.x + bv.x, 0.f) * w.x
            + fmaxf(tv.y + bv.y, 0.f) * w.y
            + fmaxf(tv.z + bv.z, 0.f) * w.z
            + fmaxf(tv.w + bv.w, 0.f) * w.w;
#pragma unroll
    for (int off = 32; off > 0; off >>= 1)
        s += __shfl_down(s, off, 64);
    if (lane == 0) out[q] = fmaxf(s + bm2[0], 0.f);
}

// ---------------- launch ----------------

extern "C" void kernel_launch(void* const* d_in, const int* in_sizes, int n_in,
                              void* d_out, int out_size, void* d_ws, size_t ws_size,
                              hipStream_t stream) {
    const float* x    = (const float*)d_in[0];
    const int*   ei   = (const int*)d_in[1];
    const int*   qry  = (const int*)d_in[2];
    const float* W1l  = (const float*)d_in[3];
    const float* b1l  = (const float*)d_in[4];
    const float* W1r  = (const float*)d_in[5];
    const float* b1r  = (const float*)d_in[6];
    const float* att1 = (const float*)d_in[7];
    const float* W2l  = (const float*)d_in[8];
    const float* b2l  = (const float*)d_in[9];
    const float* W2r  = (const float*)d_in[10];
    const float* b2r  = (const float*)d_in[11];
    const float* att2 = (const float*)d_in[12];
    const float* Wm1  = (const float*)d_in[13];
    const float* bm1  = (const float*)d_in[14];
    const float* Wm2  = (const float*)d_in[15];
    const float* bm2  = (const float*)d_in[16];
    float* out = (float*)d_out;

    // workspace carve-up (floats)
    const size_t NND = (size_t)NN * DD;          // 12.5M
    float* hbuf  = (float*)d_ws;                 // [0, NND)
    float* xl    = hbuf + NND;                   // [NND, 2*NND)
    float* xr    = xl + NND;                     // [2*NND, 3*NND)
    int* rowptr  = (int*)(xr + NND);             // NN+1
    int* fill    = rowptr + NN + 1;              // NN
    int* ssrc    = fill + NN;                    // ET
    // head precompute buffers overlay xl/xr (free by the time they're written)
    float* Ptop  = xl;                           // NN*HD = 12.8M
    float* Pbot  = xl + (size_t)NN * HD;

    dim3 blk(256);
    int gET = (ET + 255) / 256;

    // ---- CSR build (graph shared by both layers) ----
    hipMemsetAsync(fill, 0, (size_t)NN * sizeof(int), stream);
    count_kernel<<<gET, blk, 0, stream>>>(ei, fill);
    scan_kernel<<<1, 1024, 0, stream>>>(fill, rowptr);
    hipMemsetAsync(fill, 0, (size_t)NN * sizeof(int), stream);
    scatter_kernel<<<gET, blk, 0, stream>>>(ei, rowptr, fill, ssrc);

    int gNode = (NN + 3) / 4;
    dim3 gemmGrid((NN + 127) / 128, 2);   // covers N=250 and N=256

    // ---- layer 1 ----
    gemm_mfma<<<gemmGrid, blk, 0, stream>>>(x, W1l, b1l, xl, NN, FIN, DD);
    gemm_mfma<<<gemmGrid, blk, 0, stream>>>(x, W1r, b1r, xr, NN, FIN, DD);
    fused_edge_kernel<<<gNode, blk, 0, stream>>>(rowptr, ssrc, xl, xr, att1, hbuf, 1);

    // ---- layer 2 ----
    gemm_mfma<<<gemmGrid, blk, 0, stream>>>(hbuf, W2l, b2l, xl, NN, DD, DD);
    gemm_mfma<<<gemmGrid, blk, 0, stream>>>(hbuf, W2r, b2r, xr, NN, DD, DD);
    fused_edge_kernel<<<gNode, blk, 0, stream>>>(rowptr, ssrc, xl, xr, att2, hbuf, 0);
    // hbuf now holds emb [NN, DD]

    // ---- head precompute: Ptop = emb@Wm1[0:250,:] + bm1 ; Pbot = emb@Wm1[250:500,:] ----
    gemm_mfma<<<gemmGrid, blk, 0, stream>>>(hbuf, Wm1, bm1, Ptop, NN, DD, HD);
    gemm_mfma<<<gemmGrid, blk, 0, stream>>>(hbuf, Wm1 + (size_t)DD * HD, (const float*)nullptr, Pbot, NN, DD, HD);

    // ---- per-query head ----
    query_kernel<<<(NQ + 3) / 4, blk, 0, stream>>>(qry, Ptop, Pbot, Wm2, bm2, out);
}

// Round 6
// 832.973 us; speedup vs baseline: 3.8573x; 1.2012x over previous
//
#include <hip/hip_runtime.h>
#include <math.h>
#include <stdint.h>

#define NN 50000
#define NE 800000
#define ET (NE + NN)      // 850000 edges incl self loops
#define FIN 128
#define DD 250
#define HD 256
#define NQ 200000
#define NEG_SLOPE 0.2f

typedef unsigned short u16;
typedef __attribute__((ext_vector_type(8))) short bf16x8;
typedef __attribute__((ext_vector_type(4))) float f32x4;

__device__ __forceinline__ u16 f2bf_rne(float x) {
    unsigned int b = __float_as_uint(x);
    unsigned int r = (b + 0x7FFFu + ((b >> 16) & 1u)) >> 16;
    return (u16)r;
}
__device__ __forceinline__ void split2(float v, u16& h, u16& l) {
    unsigned int b = __float_as_uint(v);
    h = (u16)(b >> 16);
    float r = v - __uint_as_float(b & 0xFFFF0000u);
    l = f2bf_rne(r);
}

// ---------------- CSR build ----------------

__global__ void count_kernel(const int* __restrict__ ei, int* __restrict__ cnt) {
    int k = blockIdx.x * 256 + threadIdx.x;
    if (k >= ET) return;
    int d = (k < NE) ? ei[NE + k] : (k - NE);
    atomicAdd(&cnt[d], 1);
}

__global__ void scan_kernel(const int* __restrict__ cnt, int* __restrict__ rowptr) {
    __shared__ int buf[1024];
    __shared__ int carry;
    int t = threadIdx.x;
    if (t == 0) carry = 0;
    __syncthreads();
    for (int base = 0; base < NN; base += 1024) {
        int i = base + t;
        int v = (i < NN) ? cnt[i] : 0;
        buf[t] = v;
        __syncthreads();
        for (int off = 1; off < 1024; off <<= 1) {
            int add = (t >= off) ? buf[t - off] : 0;
            __syncthreads();
            buf[t] += add;
            __syncthreads();
        }
        if (i < NN) rowptr[i] = carry + buf[t] - v;   // exclusive
        __syncthreads();
        if (t == 1023) carry += buf[1023];
        __syncthreads();
    }
    if (t == 0) rowptr[NN] = carry;
}

__global__ void scatter_kernel(const int* __restrict__ ei,
                               const int* __restrict__ rowptr,
                               int* __restrict__ fill,
                               int* __restrict__ ssrc) {
    int k = blockIdx.x * 256 + threadIdx.x;
    if (k >= ET) return;
    int s, d;
    if (k < NE) { s = ei[k]; d = ei[NE + k]; }
    else        { s = k - NE; d = k - NE; }
    int pos = rowptr[d] + atomicAdd(&fill[d], 1);
    ssrc[pos] = s;
}

// ---------------- conversion kernels ----------------
// x [NN,128] fp32 -> split bf16 hi/lo, same layout (Kp=128)

__global__ __launch_bounds__(256) void conv_x_kernel(
    const float* __restrict__ x, u16* __restrict__ Ah, u16* __restrict__ Al)
{
    size_t idx = ((size_t)blockIdx.x * 256 + threadIdx.x) * 8;
    if (idx >= (size_t)NN * FIN) return;
    float4 v0 = *(const float4*)(x + idx);
    float4 v1 = *(const float4*)(x + idx + 4);
    float vv[8] = {v0.x, v0.y, v0.z, v0.w, v1.x, v1.y, v1.z, v1.w};
    bf16x8 h, l;
#pragma unroll
    for (int j = 0; j < 8; j++) {
        u16 hh, ll;
        split2(vv[j], hh, ll);
        h[j] = (short)hh; l[j] = (short)ll;
    }
    *(bf16x8*)(Ah + idx) = h;
    *(bf16x8*)(Al + idx) = l;
}

// W [K,N] fp32 -> WT[n][k] split bf16 hi/lo, n padded to 256, k padded to Kp=1<<kshift

__global__ __launch_bounds__(256) void conv_wT_kernel(
    const float* __restrict__ W, int K, int N, int koff, int kshift,
    u16* __restrict__ WTh, u16* __restrict__ WTl)
{
    int id = blockIdx.x * 256 + threadIdx.x;
    int Kp = 1 << kshift;
    if (id >= 256 * Kp) return;
    int n = id >> kshift, k = id & (Kp - 1);
    float v = (n < N && k < K) ? W[(size_t)(k + koff) * N + n] : 0.f;
    u16 h, l;
    split2(v, h, l);
    WTh[id] = h;
    WTl[id] = l;
}

// ---------------- pre-split bf16 MFMA pair-GEMM ----------------
// C0 = A@W0 + b0, C1 = A@W1 + b1 ; A split-bf16 [M][Kp], W* split-bf16 transposed [256][Kp]
// 128x128 tile per block over rows x cols; each block computes BOTH outputs.

__global__ __launch_bounds__(256, 2) void gemm_pair(
    const u16* __restrict__ Ah, const u16* __restrict__ Al, int Kp,
    const u16* __restrict__ B0h, const u16* __restrict__ B0l,
    const u16* __restrict__ B1h, const u16* __restrict__ B1l,
    const float* __restrict__ bias0, const float* __restrict__ bias1,
    float* __restrict__ C0, float* __restrict__ C1, int M, int N)
{
    __shared__ u16 AhS[128][32], AlS[128][32];
    __shared__ u16 BhS[2][128][32], BlS[2][128][32];

    int row0 = blockIdx.x * 128;
    int col0 = blockIdx.y * 128;
    int t = threadIdx.x;
    int lane = t & 63, w = t >> 6;
    int wr = w >> 1, wc = w & 1;
    int quad = lane >> 4, rr = lane & 15;

    f32x4 acc0[4][4], acc1[4][4];
#pragma unroll
    for (int i = 0; i < 4; i++)
#pragma unroll
        for (int j = 0; j < 4; j++) {
            acc0[i][j] = (f32x4){0.f, 0.f, 0.f, 0.f};
            acc1[i][j] = (f32x4){0.f, 0.f, 0.f, 0.f};
        }

    int ar = t >> 1, akh = (t & 1) * 16;
    int gr = row0 + ar;
    int nB = col0 + ar;
    const u16* pAh = Ah + (size_t)gr * Kp + akh;
    const u16* pAl = Al + (size_t)gr * Kp + akh;
    const u16* pB0h = B0h + (size_t)nB * Kp + akh;
    const u16* pB0l = B0l + (size_t)nB * Kp + akh;
    const u16* pB1h = B1h + (size_t)nB * Kp + akh;
    const u16* pB1l = B1l + (size_t)nB * Kp + akh;

    for (int k0 = 0; k0 < Kp; k0 += 32) {
        bf16x8 ah0{}, ah1{}, al0{}, al1{};
        if (gr < M) {
            ah0 = *(const bf16x8*)(pAh + k0);
            ah1 = *(const bf16x8*)(pAh + k0 + 8);
            al0 = *(const bf16x8*)(pAl + k0);
            al1 = *(const bf16x8*)(pAl + k0 + 8);
        }
        *(bf16x8*)&AhS[ar][akh]     = ah0;
        *(bf16x8*)&AhS[ar][akh + 8] = ah1;
        *(bf16x8*)&AlS[ar][akh]     = al0;
        *(bf16x8*)&AlS[ar][akh + 8] = al1;
        *(bf16x8*)&BhS[0][ar][akh]     = *(const bf16x8*)(pB0h + k0);
        *(bf16x8*)&BhS[0][ar][akh + 8] = *(const bf16x8*)(pB0h + k0 + 8);
        *(bf16x8*)&BlS[0][ar][akh]     = *(const bf16x8*)(pB0l + k0);
        *(bf16x8*)&BlS[0][ar][akh + 8] = *(const bf16x8*)(pB0l + k0 + 8);
        *(bf16x8*)&BhS[1][ar][akh]     = *(const bf16x8*)(pB1h + k0);
        *(bf16x8*)&BhS[1][ar][akh + 8] = *(const bf16x8*)(pB1h + k0 + 8);
        *(bf16x8*)&BlS[1][ar][akh]     = *(const bf16x8*)(pB1l + k0);
        *(bf16x8*)&BlS[1][ar][akh + 8] = *(const bf16x8*)(pB1l + k0 + 8);
        __syncthreads();

        bf16x8 fAh[4], fAl[4];
#pragma unroll
        for (int fi = 0; fi < 4; fi++) {
            int r = wr * 64 + fi * 16 + rr;
            fAh[fi] = *(const bf16x8*)&AhS[r][quad * 8];
            fAl[fi] = *(const bf16x8*)&AlS[r][quad * 8];
        }
#pragma unroll
        for (int fj = 0; fj < 4; fj++) {
            int c = wc * 64 + fj * 16 + rr;
            bf16x8 b0h = *(const bf16x8*)&BhS[0][c][quad * 8];
            bf16x8 b0l = *(const bf16x8*)&BlS[0][c][quad * 8];
            bf16x8 b1h = *(const bf16x8*)&BhS[1][c][quad * 8];
            bf16x8 b1l = *(const bf16x8*)&BlS[1][c][quad * 8];
#pragma unroll
            for (int fi = 0; fi < 4; fi++) {
                acc0[fi][fj] = __builtin_amdgcn_mfma_f32_16x16x32_bf16(fAh[fi], b0h, acc0[fi][fj], 0, 0, 0);
                acc0[fi][fj] = __builtin_amdgcn_mfma_f32_16x16x32_bf16(fAh[fi], b0l, acc0[fi][fj], 0, 0, 0);
                acc0[fi][fj] = __builtin_amdgcn_mfma_f32_16x16x32_bf16(fAl[fi], b0h, acc0[fi][fj], 0, 0, 0);
                acc1[fi][fj] = __builtin_amdgcn_mfma_f32_16x16x32_bf16(fAh[fi], b1h, acc1[fi][fj], 0, 0, 0);
                acc1[fi][fj] = __builtin_amdgcn_mfma_f32_16x16x32_bf16(fAh[fi], b1l, acc1[fi][fj], 0, 0, 0);
                acc1[fi][fj] = __builtin_amdgcn_mfma_f32_16x16x32_bf16(fAl[fi], b1h, acc1[fi][fj], 0, 0, 0);
            }
        }
        __syncthreads();
    }

    // epilogue: C/D layout col=lane&15, row=quad*4+reg
#pragma unroll
    for (int fj = 0; fj < 4; fj++) {
        int gc = col0 + wc * 64 + fj * 16 + rr;
        if (gc >= N) continue;
        float bb0 = bias0 ? bias0[gc] : 0.f;
        float bb1 = bias1 ? bias1[gc] : 0.f;
#pragma unroll
        for (int fi = 0; fi < 4; fi++) {
#pragma unroll
            for (int r = 0; r < 4; r++) {
                int grr = row0 + wr * 64 + fi * 16 + quad * 4 + r;
                if (grr < M) {
                    C0[(size_t)grr * N + gc] = acc0[fi][fj][r] + bb0;
                    C1[(size_t)grr * N + gc] = acc1[fi][fj][r] + bb1;
                }
            }
        }
    }
}

// ---------------- fused edge phase: single-pass online softmax + aggregate ----------------
// output written directly as split bf16 hi/lo [NN][256] (k 250..255 zero-padded)

__device__ __forceinline__ float edge_e(float4 xv, float4 xrv, float4 atv) {
    float vx = xv.x + xrv.x; vx = (vx > 0.f) ? vx : NEG_SLOPE * vx;
    float vy = xv.y + xrv.y; vy = (vy > 0.f) ? vy : NEG_SLOPE * vy;
    float vz = xv.z + xrv.z; vz = (vz > 0.f) ? vz : NEG_SLOPE * vz;
    float vw = xv.w + xrv.w; vw = (vw > 0.f) ? vw : NEG_SLOPE * vw;
    return vx * atv.x + vy * atv.y + vz * atv.z + vw * atv.w;
}

__global__ __launch_bounds__(256) void fused_edge_kernel(
    const int* __restrict__ rowptr, const int* __restrict__ ssrc,
    const float* __restrict__ xl, const float* __restrict__ xr,
    const float* __restrict__ att,
    u16* __restrict__ Oh, u16* __restrict__ Ol, int dorelu)
{
    int i = blockIdx.x * 4 + (threadIdx.x >> 6);
    if (i >= NN) return;
    int lane = threadIdx.x & 63;
    int beg = rowptr[i], end = rowptr[i + 1];
    int d0 = lane * 4;
    bool full = (d0 + 3 < DD);      // lanes 0..61
    bool half = (!full && d0 < DD); // lane 62 -> 2 elems

    float4 xrv = make_float4(0.f, 0.f, 0.f, 0.f);
    float4 atv = make_float4(0.f, 0.f, 0.f, 0.f);
    if (full) {
        xrv = *(const float4*)&xr[(size_t)i * DD + d0];
        atv = *(const float4*)&att[d0];
    } else if (half) {
        xrv.x = xr[(size_t)i * DD + d0];     xrv.y = xr[(size_t)i * DD + d0 + 1];
        atv.x = att[d0];                     atv.y = att[d0 + 1];
    }

    float m = -1e30f, ssum = 0.f;
    float4 acc = make_float4(0.f, 0.f, 0.f, 0.f);

    int p = beg;
    for (; p + 3 < end; p += 4) {
        int s0 = ssrc[p], s1 = ssrc[p + 1], s2 = ssrc[p + 2], s3 = ssrc[p + 3];
        float4 x0 = make_float4(0.f, 0.f, 0.f, 0.f);
        float4 x1 = x0, x2 = x0, x3 = x0;
        if (full) {
            x0 = *(const float4*)&xl[(size_t)s0 * DD + d0];
            x1 = *(const float4*)&xl[(size_t)s1 * DD + d0];
            x2 = *(const float4*)&xl[(size_t)s2 * DD + d0];
            x3 = *(const float4*)&xl[(size_t)s3 * DD + d0];
        } else if (half) {
            x0.x = xl[(size_t)s0 * DD + d0]; x0.y = xl[(size_t)s0 * DD + d0 + 1];
            x1.x = xl[(size_t)s1 * DD + d0]; x1.y = xl[(size_t)s1 * DD + d0 + 1];
            x2.x = xl[(size_t)s2 * DD + d0]; x2.y = xl[(size_t)s2 * DD + d0 + 1];
            x3.x = xl[(size_t)s3 * DD + d0]; x3.y = xl[(size_t)s3 * DD + d0 + 1];
        }
        float e0 = edge_e(x0, xrv, atv);
        float e1 = edge_e(x1, xrv, atv);
        float e2 = edge_e(x2, xrv, atv);
        float e3 = edge_e(x3, xrv, atv);
#pragma unroll
        for (int off = 1; off < 64; off <<= 1) {
            e0 += __shfl_xor(e0, off, 64);
            e1 += __shfl_xor(e1, off, 64);
            e2 += __shfl_xor(e2, off, 64);
            e3 += __shfl_xor(e3, off, 64);
        }
        float nm = fmaxf(fmaxf(m, e0), fmaxf(fmaxf(e1, e2), e3));
        float sc = __expf(m - nm);
        float w0 = __expf(e0 - nm);
        float w1 = __expf(e1 - nm);
        float w2 = __expf(e2 - nm);
        float w3 = __expf(e3 - nm);
        acc.x = acc.x * sc + w0 * x0.x + w1 * x1.x + w2 * x2.x + w3 * x3.x;
        acc.y = acc.y * sc + w0 * x0.y + w1 * x1.y + w2 * x2.y + w3 * x3.y;
        acc.z = acc.z * sc + w0 * x0.z + w1 * x1.z + w2 * x2.z + w3 * x3.z;
        acc.w = acc.w * sc + w0 * x0.w + w1 * x1.w + w2 * x2.w + w3 * x3.w;
        ssum = ssum * sc + (w0 + w1) + (w2 + w3);
        m = nm;
    }
    for (; p < end; p++) {
        int s = ssrc[p];
        float4 xv = make_float4(0.f, 0.f, 0.f, 0.f);
        if (full)      xv = *(const float4*)&xl[(size_t)s * DD + d0];
        else if (half) { xv.x = xl[(size_t)s * DD + d0]; xv.y = xl[(size_t)s * DD + d0 + 1]; }
        float e = edge_e(xv, xrv, atv);
#pragma unroll
        for (int off = 1; off < 64; off <<= 1)
            e += __shfl_xor(e, off, 64);
        float nm = fmaxf(m, e);
        float sc = __expf(m - nm);
        float w = __expf(e - nm);
        acc.x = acc.x * sc + w * xv.x;
        acc.y = acc.y * sc + w * xv.y;
        acc.z = acc.z * sc + w * xv.z;
        acc.w = acc.w * sc + w * xv.w;
        ssum = ssum * sc + w;
        m = nm;
    }

    float inv = 1.f / ssum;
    acc.x *= inv; acc.y *= inv; acc.z *= inv; acc.w *= inv;
    if (dorelu) {
        acc.x = fmaxf(acc.x, 0.f); acc.y = fmaxf(acc.y, 0.f);
        acc.z = fmaxf(acc.z, 0.f); acc.w = fmaxf(acc.w, 0.f);
    }
    // split-write (invalid lanes carry exact zeros -> pad written as 0)
    size_t base = (size_t)i * 256 + d0;
    u16 hx, lx, hy, ly, hz, lz, hw, lw;
    split2(acc.x, hx, lx); split2(acc.y, hy, ly);
    split2(acc.z, hz, lz); split2(acc.w, hw, lw);
    ushort4 hv; hv.x = hx; hv.y = hy; hv.z = hz; hv.w = hw;
    ushort4 lv; lv.x = lx; lv.y = ly; lv.z = lz; lv.w = lw;
    *(ushort4*)&Oh[base] = hv;
    *(ushort4*)&Ol[base] = lv;
}

// ---------------- query head: out[q] = relu( relu(Ptop[a]+Pbot[b]) . Wm2 + bm2 ) ----------------

__global__ __launch_bounds__(256) void query_kernel(
    const int* __restrict__ qry, const float* __restrict__ Ptop,
    const float* __restrict__ Pbot, const float* __restrict__ Wm2,
    const float* __restrict__ bm2, float* __restrict__ out)
{
    int q = blockIdx.x * 4 + (threadIdx.x >> 6);
    if (q >= NQ) return;
    int lane = threadIdx.x & 63;
    int a = qry[q * 2 + 0], b = qry[q * 2 + 1];
    float4 tv = *(const float4*)&Ptop[(size_t)a * HD + lane * 4];
    float4 bv = *(const float4*)&Pbot[(size_t)b * HD + lane * 4];
    float4 w  = *(const float4*)&Wm2[lane * 4];
    float s = fmaxf(tv.x + bv.x, 0.f) * w.x
            + fmaxf(tv.y + bv.y, 0.f) * w.y
            + fmaxf(tv.z + bv.z, 0.f) * w.z
            + fmaxf(tv.w + bv.w, 0.f) * w.w;
#pragma unroll
    for (int off = 32; off > 0; off >>= 1)
        s += __shfl_down(s, off, 64);
    if (lane == 0) out[q] = fmaxf(s + bm2[0], 0.f);
}

// ---------------- launch ----------------

extern "C" void kernel_launch(void* const* d_in, const int* in_sizes, int n_in,
                              void* d_out, int out_size, void* d_ws, size_t ws_size,
                              hipStream_t stream) {
    const float* x    = (const float*)d_in[0];
    const int*   ei   = (const int*)d_in[1];
    const int*   qry  = (const int*)d_in[2];
    const float* W1l  = (const float*)d_in[3];
    const float* b1l  = (const float*)d_in[4];
    const float* W1r  = (const float*)d_in[5];
    const float* b1r  = (const float*)d_in[6];
    const float* att1 = (const float*)d_in[7];
    const float* W2l  = (const float*)d_in[8];
    const float* b2l  = (const float*)d_in[9];
    const float* W2r  = (const float*)d_in[10];
    const float* b2r  = (const float*)d_in[11];
    const float* att2 = (const float*)d_in[12];
    const float* Wm1  = (const float*)d_in[13];
    const float* bm1  = (const float*)d_in[14];
    const float* Wm2  = (const float*)d_in[15];
    const float* bm2  = (const float*)d_in[16];
    float* out = (float*)d_out;

    // workspace carve-up
    const size_t NND = (size_t)NN * DD;          // 12.5M floats
    float* xl    = (float*)d_ws;                 // [0, NND)
    float* xr    = xl + NND;                     // [NND, 2*NND)
    int* rowptr  = (int*)(xr + NND);             // NN+1
    int* fill    = rowptr + NN + 1;              // NN
    int* ssrc    = fill + NN;                    // ET
    uintptr_t wp = (uintptr_t)(ssrc + ET);
    wp = (wp + 63) & ~(uintptr_t)63;
    u16* W1lTh = (u16*)wp;                       // 256*128 each
    u16* W1lTl = W1lTh + 256 * 128;
    u16* W1rTh = W1lTl + 256 * 128;
    u16* W1rTl = W1rTh + 256 * 128;
    u16* W2lTh = W1rTl + 256 * 128;              // 256*256 each from here
    u16* W2lTl = W2lTh + 65536;
    u16* W2rTh = W2lTl + 65536;
    u16* W2rTl = W2rTh + 65536;
    u16* WmtTh = W2rTl + 65536;
    u16* WmtTl = WmtTh + 65536;
    u16* WmbTh = WmtTl + 65536;
    u16* WmbTl = WmbTh + 65536;
    u16* Asph  = WmbTl + 65536;                  // NN*256 (also holds x-split [NN][128] early)
    u16* Aspl  = Asph + (size_t)NN * 256;
    // head buffers overlay xl/xr/csr (all dead by then); end 102.4MB < Asp base ~105MB
    float* Ptop  = xl;
    float* Pbot  = xl + (size_t)NN * HD;

    dim3 blk(256);
    int gET = (ET + 255) / 256;
    int gNode = (NN + 3) / 4;
    dim3 gg((NN + 127) / 128, 2);

    // ---- conversions (independent of CSR) ----
    conv_x_kernel<<<(NN * FIN / 8 + 255) / 256, blk, 0, stream>>>(x, Asph, Aspl);
    conv_wT_kernel<<<128, blk, 0, stream>>>(W1l, FIN, DD, 0, 7, W1lTh, W1lTl);
    conv_wT_kernel<<<128, blk, 0, stream>>>(W1r, FIN, DD, 0, 7, W1rTh, W1rTl);
    conv_wT_kernel<<<256, blk, 0, stream>>>(W2l, DD, DD, 0, 8, W2lTh, W2lTl);
    conv_wT_kernel<<<256, blk, 0, stream>>>(W2r, DD, DD, 0, 8, W2rTh, W2rTl);
    conv_wT_kernel<<<256, blk, 0, stream>>>(Wm1, DD, HD, 0, 8, WmtTh, WmtTl);
    conv_wT_kernel<<<256, blk, 0, stream>>>(Wm1, DD, HD, DD, 8, WmbTh, WmbTl);

    // ---- CSR build (graph shared by both layers) ----
    hipMemsetAsync(fill, 0, (size_t)NN * sizeof(int), stream);
    count_kernel<<<gET, blk, 0, stream>>>(ei, fill);
    scan_kernel<<<1, 1024, 0, stream>>>(fill, rowptr);
    hipMemsetAsync(fill, 0, (size_t)NN * sizeof(int), stream);
    scatter_kernel<<<gET, blk, 0, stream>>>(ei, rowptr, fill, ssrc);

    // ---- layer 1 (A = x-split, Kp=128) ----
    gemm_pair<<<gg, blk, 0, stream>>>(Asph, Aspl, 128, W1lTh, W1lTl, W1rTh, W1rTl,
                                      b1l, b1r, xl, xr, NN, DD);
    fused_edge_kernel<<<gNode, blk, 0, stream>>>(rowptr, ssrc, xl, xr, att1, Asph, Aspl, 1);

    // ---- layer 2 (A = h-split, Kp=256) ----
    gemm_pair<<<gg, blk, 0, stream>>>(Asph, Aspl, 256, W2lTh, W2lTl, W2rTh, W2rTl,
                                      b2l, b2r, xl, xr, NN, DD);
    fused_edge_kernel<<<gNode, blk, 0, stream>>>(rowptr, ssrc, xl, xr, att2, Asph, Aspl, 0);

    // ---- head precompute (A = emb-split, Kp=256) ----
    gemm_pair<<<gg, blk, 0, stream>>>(Asph, Aspl, 256, WmtTh, WmtTl, WmbTh, WmbTl,
                                      bm1, (const float*)nullptr, Ptop, Pbot, NN, HD);

    // ---- per-query head ----
    query_kernel<<<(NQ + 3) / 4, blk, 0, stream>>>(qry, Ptop, Pbot, Wm2, bm2, out);
}